// Round 14
// baseline (1404.217 us; speedup 1.0000x reference)
//
#include <hip/hip_runtime.h>
#include <hip/hip_bf16.h>

namespace {

constexpr int NN   = 8192;    // nodes
constexpr int NE   = 131072;  // edges
constexpr int SD   = 256;     // SDIM
constexpr int ED   = 128;     // EDIM
constexpr int NL   = 5;       // layers
constexpr int DINc = 644;     // 2*SD + ED + 4
constexpr int KE   = 160;     // edge-GEMM K: 128 e + 4 scalars + pad
constexpr int TE   = 5;       // KE/32
constexpr int T2   = 8;       // 256/32
constexpr int DOUTc= 513;
constexpr int HIDc = 256;

typedef __bf16 bf16x8 __attribute__((ext_vector_type(8)));
typedef float  f32x4  __attribute__((ext_vector_type(4)));

__device__ __forceinline__ float siluf(float x) { return x / (1.0f + __expf(-x)); }

// async global->LDS, 16B/lane. LDS dest is wave-uniform base (+lane*16 in HW).
__device__ __forceinline__ void gl_lds16(const void* gsrc, void* lds_uniform_base) {
  __builtin_amdgcn_global_load_lds(
      (const __attribute__((address_space(1))) unsigned int*)gsrc,
      (__attribute__((address_space(3))) unsigned int*)lds_uniform_base, 16, 0, 0);
}

__device__ __forceinline__ void wait_vm4() {
  asm volatile("s_waitcnt vmcnt(4)" ::: "memory");
  __builtin_amdgcn_sched_barrier(0);
}
__device__ __forceinline__ void wait_vm0() {
  asm volatile("s_waitcnt vmcnt(0)" ::: "memory");
  __builtin_amdgcn_sched_barrier(0);
}

// bank-group swizzle: (5x)&7 is a permutation on 0..7.
__device__ __host__ __forceinline__ int swz(int kc) { return (kc * 5) & 7; }
__device__ __forceinline__ int bpos(int kc, int n)   { return kc * 256 + (n   ^ swz(kc)); }
// position of 16B chunk (kc,row) in a [NC][64]-chunk panel (Hsh / Apan layout)
__device__ __forceinline__ int ppos(int kc, int row) { return kc * 64 + (row ^ swz(kc & 3)); }

enum { SRC_BF16 = 1 };

struct GemmArgs {
  const __hip_bfloat16* Wt;     // swizzled B stream
  const float* bias;
  const __hip_bfloat16* Abf;
  __hip_bfloat16* bf_out;
  const __hip_bfloat16* Wtb;    // dual second half
  const float* biasb;
  __hip_bfloat16* bf_outb;
  int dual;
};

__device__ __forceinline__ uint4 cvt8f(const float* p) {
  alignas(16) __hip_bfloat16 t8[8];
#pragma unroll
  for (int i = 0; i < 8; i++) t8[i] = __float2bfloat16(p[i]);
  return *(const uint4*)t8;
}

// Layer-0 P1/P2: BM=64, BN=256, dual-launch. A-panel staged once; barrier-free loop.
template<int KTOT, int BM>
__global__ __launch_bounds__(256) void gemm_k(GemmArgs g) {
  constexpr int T = KTOT / 32;
  constexpr int NC = KTOT / 8;
  constexpr int RPT = 256 / BM;
  constexpr int RMASK = RPT - 1;
  __shared__ alignas(16) unsigned short Apan[NC * BM * 8];
  __shared__ alignas(16) unsigned short Bsh[2][4 * 256 * 8];
  const int tid = threadIdx.x, lane = tid & 63, wave = tid >> 6;
  const int l16 = lane & 15, lhi = lane >> 4;
  const __hip_bfloat16* wtp = g.Wt;
  const float* biasp = g.bias;
  __hip_bfloat16* outp = g.bf_out;
  int blk = blockIdx.x;
  {
    const int half = gridDim.x >> 1;
    if (g.dual && blk >= half) { blk -= half; wtp = g.Wtb; biasp = g.biasb; outp = g.bf_outb; }
  }
  const int row0 = blk * BM;
  const int ar = tid / RPT, aq = tid % RPT;
  const int arow = row0 + ar;
  f32x4 acc[BM / 16][4] = {};

  auto issueB = [&](int t, int buf) {
    const __hip_bfloat16* src = wtp + (size_t)t * 1024 * 8;
    unsigned short* dst = &Bsh[buf][0];
#pragma unroll
    for (int i = 0; i < 4; i++)
      gl_lds16(src + (size_t)(i * 256 + wave * 64 + lane) * 8, dst + (i * 256 + wave * 64) * 8);
  };

  issueB(0, 0);
#pragma unroll
  for (int j = 0; j < NC / RPT; j++) {
    const int c = j * RPT + aq;
    uint4 o = *(const uint4*)(g.Abf + (size_t)arow * KTOT + c * 8);
    *(uint4*)&Apan[(c * BM + (ar ^ swz(aq))) * 8] = o;
  }
  __syncthreads();

  int cur = 0;
  for (int t = 0; t < T; ++t) {
    if (t + 1 < T) { issueB(t + 1, cur ^ 1); wait_vm4(); }
    else           { wait_vm0(); }
    bf16x8 bfr[4];
#pragma unroll
    for (int f = 0; f < 4; f++)
      bfr[f] = *(const bf16x8*)&Bsh[cur][bpos(lhi, wave * 64 + f * 16 + l16) * 8];
#pragma unroll
    for (int fr = 0; fr < BM / 16; fr++) {
      const int kc = t * 4 + lhi;
      const bf16x8 afr = *(const bf16x8*)&Apan[(kc * BM + ((fr * 16 + l16) ^ swz(kc & RMASK))) * 8];
#pragma unroll
      for (int fc = 0; fc < 4; fc++)
        acc[fr][fc] = __builtin_amdgcn_mfma_f32_16x16x32_bf16(afr, bfr[fc], acc[fr][fc], 0, 0, 0);
    }
    cur ^= 1;
  }

#pragma unroll
  for (int fr = 0; fr < BM / 16; fr++) {
#pragma unroll
    for (int fc = 0; fc < 4; fc++) {
      const int n = wave * 64 + fc * 16 + l16;
#pragma unroll
      for (int r = 0; r < 4; r++) {
        const int row = row0 + fr * 16 + lhi * 4 + r;
        outp[(size_t)row * HIDc + n] = __float2bfloat16(acc[fr][fc][r] + biasp[n]);
      }
    }
  }
}

// ==== fused node kernel: s-update + node MLP + next-layer LN + P1/P2 ====
struct Node3Args {
  const __hip_bfloat16* W2a;
  const __hip_bfloat16* U1s;
  const __hip_bfloat16* U2s;
  const __hip_bfloat16* W1an;   // next layer streams
  const __hip_bfloat16* W1bn;
  const float* b2L;
  const float* bU1;
  const float* bU2;
  const float* b1n;             // next layer b1
  const float* lng;             // next layer ln params
  const float* lnb;
  const float* Hagg;
  const int* rawcnt;
  float* s_out;
  __hip_bfloat16* p1;
  __hip_bfloat16* p2;
};

template<int LAST>
__global__ __launch_bounds__(256) void node3_k(Node3Args g) {
  constexpr int BM = 32, RPT = 8, NC = 32, T = 8;
  __shared__ alignas(16) unsigned short Apan[NC * BM * 8];      // 16 KB
  __shared__ alignas(16) unsigned short Bsh[2][4 * 256 * 8];    // 32 KB
  __shared__ float red[2][4][32];
  const int tid = threadIdx.x, lane = tid & 63, wave = tid >> 6;
  const int l16 = lane & 15, lhi = lane >> 4;
  const int row0 = blockIdx.x * BM;
  const int ar = tid >> 3, aq = tid & 7;

  auto issueB = [&](const __hip_bfloat16* W, int t, int buf) {
    const __hip_bfloat16* src = W + (size_t)t * 1024 * 8;
    unsigned short* dst = &Bsh[buf][0];
#pragma unroll
    for (int i = 0; i < 4; i++)
      gl_lds16(src + (size_t)(i * 256 + wave * 64 + lane) * 8, dst + (i * 256 + wave * 64) * 8);
  };

  f32x4 acc[4][2];   // SWAPPED: acc[n-blk][row-blk], D[n][row]
  auto kloop = [&](const __hip_bfloat16* W) {
#pragma unroll
    for (int i = 0; i < 4; i++)
#pragma unroll
      for (int j = 0; j < 2; j++) acc[i][j] = f32x4{0.f, 0.f, 0.f, 0.f};
    int cur = 0;
    for (int t = 0; t < T; ++t) {
      if (t + 1 < T) { issueB(W, t + 1, cur ^ 1); wait_vm4(); }
      else           { wait_vm0(); }
      bf16x8 wfr[4], afr[2];
#pragma unroll
      for (int f = 0; f < 4; f++)
        wfr[f] = *(const bf16x8*)&Bsh[cur][bpos(lhi, wave * 64 + f * 16 + l16) * 8];
#pragma unroll
      for (int f = 0; f < 2; f++) {
        const int kc = t * 4 + lhi;
        afr[f] = *(const bf16x8*)&Apan[(kc * BM + ((f * 16 + l16) ^ swz(kc & 7))) * 8];
      }
#pragma unroll
      for (int fr = 0; fr < 4; fr++)
#pragma unroll
        for (int fc = 0; fc < 2; fc++)
          acc[fr][fc] = __builtin_amdgcn_mfma_f32_16x16x32_bf16(wfr[fr], afr[fc], acc[fr][fc], 0, 0, 0);
      cur ^= 1;
    }
  };

  // ---- stage Hagg panel (f32 -> bf16)
  issueB(g.W2a, 0, 0);
#pragma unroll
  for (int j = 0; j < NC / RPT; j++) {
    const int c = j * RPT + aq;
    uint4 o = cvt8f(g.Hagg + (size_t)(row0 + ar) * SD + c * 8);
    *(uint4*)&Apan[(c * BM + (ar ^ swz(aq))) * 8] = o;
  }
  __syncthreads();

  // ---- step A: Hagg @ W2a -> s1
  kloop(g.W2a);
  __syncthreads();
  if constexpr (!LAST) issueB(g.U1s, 0, 0);

#pragma unroll
  for (int fr = 0; fr < 4; fr++) {
    const int nb = wave * 64 + fr * 16 + lhi * 4;
    const int kc = nb >> 3, off = nb & 7;
    const f32x4 b4 = *(const f32x4*)(g.b2L + nb);
#pragma unroll
    for (int fc = 0; fc < 2; fc++) {
      const int row = fc * 16 + l16;
      const float rc = (float)g.rawcnt[row0 + row];
      float* sp = g.s_out + (size_t)(row0 + row) * SD + nb;
      f32x4 sold = *(const f32x4*)sp;
      alignas(8) __hip_bfloat16 hb[4];
      f32x4 s1;
#pragma unroll
      for (int r = 0; r < 4; r++) {
        s1[r] = sold[r] + acc[fr][fc][r] + rc * b4[r];
        hb[r] = __float2bfloat16(s1[r]);
      }
      *(f32x4*)sp = s1;
      if constexpr (!LAST)
        *(uint2*)&Apan[(kc * BM + (row ^ swz(kc & 7))) * 8 + off] = *(const uint2*)hb;
    }
  }
  if constexpr (LAST) return;

  __syncthreads();   // s1 panel visible; U1(0) landed

  // ---- step B: t = silu(s1@U1 + bU1) -> Apan
  kloop(g.U1s);
  __syncthreads();
  issueB(g.U2s, 0, 0);
#pragma unroll
  for (int fr = 0; fr < 4; fr++) {
    const int nb = wave * 64 + fr * 16 + lhi * 4;
    const int kc = nb >> 3, off = nb & 7;
    const f32x4 b4 = *(const f32x4*)(g.bU1 + nb);
#pragma unroll
    for (int fc = 0; fc < 2; fc++) {
      const int row = fc * 16 + l16;
      alignas(8) __hip_bfloat16 hb[4];
#pragma unroll
      for (int r = 0; r < 4; r++)
        hb[r] = __float2bfloat16(siluf(acc[fr][fc][r] + b4[r]));
      *(uint2*)&Apan[(kc * BM + (row ^ swz(kc & 7))) * 8 + off] = *(const uint2*)hb;
    }
  }
  __syncthreads();   // t panel visible; U2(0) landed

  // ---- step C: s2 = s1 + t@U2 + bU2 (s_o RMW); row stats for LN
  kloop(g.U2s);
  float psum[2] = {0.f, 0.f}, psq[2] = {0.f, 0.f};
#pragma unroll
  for (int fr = 0; fr < 4; fr++) {
    const int nb = wave * 64 + fr * 16 + lhi * 4;
    const f32x4 b4 = *(const f32x4*)(g.bU2 + nb);
#pragma unroll
    for (int fc = 0; fc < 2; fc++) {
      const int row = fc * 16 + l16;
      float* sp = g.s_out + (size_t)(row0 + row) * SD + nb;
      f32x4 sv = *(const f32x4*)sp;
#pragma unroll
      for (int r = 0; r < 4; r++) {
        sv[r] += acc[fr][fc][r] + b4[r];
        psum[fc] += sv[r];
        psq[fc] += sv[r] * sv[r];
      }
      *(f32x4*)sp = sv;
      acc[fr][fc] = sv;   // keep s2 in regs
    }
  }
#pragma unroll
  for (int fc = 0; fc < 2; fc++) {
    psum[fc] += __shfl_xor(psum[fc], 16); psum[fc] += __shfl_xor(psum[fc], 32);
    psq[fc]  += __shfl_xor(psq[fc], 16);  psq[fc]  += __shfl_xor(psq[fc], 32);
  }
  if (lane < 16) {
    red[0][wave][lane] = psum[0]; red[0][wave][16 + lane] = psum[1];
    red[1][wave][lane] = psq[0];  red[1][wave][16 + lane] = psq[1];
  }
  __syncthreads();   // red visible; all waves done reading Apan (t-panel)

  float mu2[2], rs2[2];
#pragma unroll
  for (int fc = 0; fc < 2; fc++) {
    const int ri = fc * 16 + l16;
    const float S = red[0][0][ri] + red[0][1][ri] + red[0][2][ri] + red[0][3][ri];
    const float Q = red[1][0][ri] + red[1][1][ri] + red[1][2][ri] + red[1][3][ri];
    const float mu = S * (1.0f / SD);
    const float var = Q * (1.0f / SD) - mu * mu;
    mu2[fc] = mu; rs2[fc] = rsqrtf(var + 1e-5f);
  }
  // ---- s_ln = LN_{l+1}(s2) -> Apan
#pragma unroll
  for (int fr = 0; fr < 4; fr++) {
    const int nb = wave * 64 + fr * 16 + lhi * 4;
    const int kc = nb >> 3, off = nb & 7;
    const f32x4 g4 = *(const f32x4*)(g.lng + nb);
    const f32x4 bb4 = *(const f32x4*)(g.lnb + nb);
#pragma unroll
    for (int fc = 0; fc < 2; fc++) {
      const int row = fc * 16 + l16;
      alignas(8) __hip_bfloat16 hb[4];
#pragma unroll
      for (int r = 0; r < 4; r++)
        hb[r] = __float2bfloat16(g4[r] * (acc[fr][fc][r] - mu2[fc]) * rs2[fc] + bb4[r]);
      *(uint2*)&Apan[(kc * BM + (row ^ swz(kc & 7))) * 8 + off] = *(const uint2*)hb;
    }
  }
  issueB(g.W1an, 0, 0);
  __syncthreads();   // s_ln panel visible; W1a(0) landed

  // ---- step D: P1 = s_ln @ W1a_{l+1} + b1_{l+1}
  kloop(g.W1an);
#pragma unroll
  for (int fr = 0; fr < 4; fr++) {
    const int nb = wave * 64 + fr * 16 + lhi * 4;
    const f32x4 b4 = *(const f32x4*)(g.b1n + nb);
#pragma unroll
    for (int fc = 0; fc < 2; fc++) {
      const int row = fc * 16 + l16;
      alignas(8) __hip_bfloat16 hb[4];
#pragma unroll
      for (int r = 0; r < 4; r++)
        hb[r] = __float2bfloat16(acc[fr][fc][r] + b4[r]);
      *(uint2*)(g.p1 + (size_t)(row0 + row) * SD + nb) = *(const uint2*)hb;
    }
  }
  // ---- step E: P2 = s_ln @ W1b_{l+1}
  issueB(g.W1bn, 0, 0);
  kloop(g.W1bn);
#pragma unroll
  for (int fr = 0; fr < 4; fr++) {
    const int nb = wave * 64 + fr * 16 + lhi * 4;
#pragma unroll
    for (int fc = 0; fc < 2; fc++) {
      const int row = fc * 16 + l16;
      alignas(8) __hip_bfloat16 hb[4];
#pragma unroll
      for (int r = 0; r < 4; r++)
        hb[r] = __float2bfloat16(acc[fr][fc][r]);
      *(uint2*)(g.p2 + (size_t)(row0 + row) * SD + nb) = *(const uint2*)hb;
    }
  }
}

// ==== fused edge kernel: barrier-free phase-1 (edge A-panel staged once in Hsh) ====
struct FusedArgs {
  const __hip_bfloat16* W1e;
  const __hip_bfloat16* W2s;
  const float* b2L;
  const int* src; const int* tgt;
  const int* rank;
  const float* pos;             // p_o [NN][3]
  const __hip_bfloat16* e_bf;
  const __hip_bfloat16* p1;
  const __hip_bfloat16* p2;
  const __hip_bfloat16* w384;
  float* rnp;                   // [NE][3] out, PERMUTED
  float* mp;                    // [NE][3] out, PERMUTED
  __hip_bfloat16* h_out;        // [NE][256], PERMUTED
  __hip_bfloat16* wv_out;       // [NE][128], PERMUTED
  __hip_bfloat16* e_bf_out;     // [NE][128], edge order
  float* e_f32_out;             // d_out e region, edge order
  int write_e_f32;
};

__global__ __launch_bounds__(256) void fused_k(FusedArgs g) {
  __shared__ alignas(16) unsigned short Bsh[2][4 * 256 * 8];    // 32 KB (W stream dbuf)
  __shared__ alignas(16) unsigned short Hsh[32 * 64 * 8];       // 32 KB (edge-A -> psum -> h)
  __shared__ float wps[4][64];
  __shared__ float RnL[64][3];
  __shared__ int Rk[64];
  const int tid = threadIdx.x, lane = tid & 63, wave = tid >> 6;
  const int l16 = lane & 15, lhi = lane >> 4;
  const int row0 = blockIdx.x * 64;
  const int ar = tid >> 2, aq = tid & 3;
  const int arow = row0 + ar;
  const int sn = g.src[arow], tn = g.tgt[arow];

  auto issueW = [&](const __hip_bfloat16* W, int t, int buf) {
    const __hip_bfloat16* src = W + (size_t)t * 1024 * 8;
    unsigned short* dst = &Bsh[buf][0];
#pragma unroll
    for (int i = 0; i < 4; i++)
      gl_lds16(src + (size_t)(i * 256 + wave * 64 + lane) * 8, dst + (i * 256 + wave * 64) * 8);
  };

  issueW(g.W1e, 0, 0);

  // ---- psum gather (issued early; completes at the prologue barrier)
  uint4 r1[8], r2[8];
#pragma unroll
  for (int j = 0; j < 8; j++) {
    const int c = j * 4 + aq;
    r1[j] = *(const uint4*)(g.p1 + (size_t)sn * SD + c * 8);
    r2[j] = *(const uint4*)(g.p2 + (size_t)tn * SD + c * 8);
  }

  // ---- in-kernel edge attrs; tail chunk (c=16) written directly by attr threads
  if (tid < 64) {
    const int e = row0 + tid;
    const int rk = g.rank[e];
    Rk[tid] = rk;
    const int s_ = g.src[e], t_ = g.tgt[e];
    const float sx = g.pos[s_ * 3], sy = g.pos[s_ * 3 + 1], sz = g.pos[s_ * 3 + 2];
    const float tx = g.pos[t_ * 3], ty = g.pos[t_ * 3 + 1], tz = g.pos[t_ * 3 + 2];
    const float rx = tx - sx, ry = ty - sy, rz = tz - sz;
    const float av = tx * sx + ty * sy + tz * sz;
    const float rr = rx * rx + ry * ry + rz * rz;
    const float d = sqrtf(fmaxf(rr, 1e-6f));
    const float inv = 1.0f / (1.0f + d);
    const float r0 = rx * inv, r1v = ry * inv, r2v = rz * inv;
    RnL[tid][0] = r0; RnL[tid][1] = r1v; RnL[tid][2] = r2v;
    g.rnp[rk * 3] = r0; g.rnp[rk * 3 + 1] = r1v; g.rnp[rk * 3 + 2] = r2v;
    alignas(16) __hip_bfloat16 q8[8];
    q8[0] = __float2bfloat16(d);
    q8[1] = __float2bfloat16(av);
    q8[2] = __float2bfloat16(sqrtf(sx * sx + sy * sy + sz * sz));
    q8[3] = __float2bfloat16(sqrtf(tx * tx + ty * ty + tz * tz));
    q8[4] = q8[5] = q8[6] = q8[7] = __float2bfloat16(0.0f);
    *(uint4*)&Hsh[ppos(16, tid) * 8] = *(const uint4*)q8;   // swz(16&3)=0
  } else {
    // zero chunks 17..19 (k = 136..159): threads aq in {1,2,3}, any ar
  }
  if (aq > 0) {
    uint4 z; z.x = z.y = z.z = z.w = 0;
    *(uint4*)&Hsh[ppos(16 + aq, ar) * 8] = z;
  }
  // ---- edge A-panel chunks 0..15 (e features)
#pragma unroll
  for (int j = 0; j < 4; j++) {
    const int c = j * 4 + aq;
    uint4 o = *(const uint4*)(g.e_bf + (size_t)arow * ED + c * 8);
    *(uint4*)&Hsh[ppos(c, ar) * 8] = o;
  }
  __syncthreads();   // A-panel + attrs visible; W1e(0) + psum loads drained

  // pre-add psum to bf16 (frees r1/r2 regs before phase-1)
  uint4 ps[8];
#pragma unroll
  for (int j = 0; j < 8; j++) {
    const __hip_bfloat16* h1 = (const __hip_bfloat16*)&r1[j];
    const __hip_bfloat16* h2 = (const __hip_bfloat16*)&r2[j];
    alignas(16) __hip_bfloat16 o8[8];
#pragma unroll
    for (int m = 0; m < 8; m++)
      o8[m] = __float2bfloat16(__bfloat162float(h1[m]) + __bfloat162float(h2[m]));
    ps[j] = *(const uint4*)o8;
  }

  // ---- phase 1: SWAPPED operands -> D[n][row]; BARRIER-FREE (A static in Hsh,
  // B wave-private Bsh[2] dbuf, counted vmcnt).
  f32x4 acc1[4][4] = {};
  int cur = 0;
  for (int t = 0; t < TE; ++t) {
    if (t + 1 < TE) { issueW(g.W1e, t + 1, cur ^ 1); wait_vm4(); }
    else            { wait_vm0(); }
    bf16x8 wfr[4], efr[4];
#pragma unroll
    for (int f = 0; f < 4; f++) {
      wfr[f] = *(const bf16x8*)&Bsh[cur][bpos(lhi, wave * 64 + f * 16 + l16) * 8];
      efr[f] = *(const bf16x8*)&Hsh[ppos(t * 4 + lhi, f * 16 + l16) * 8];
    }
#pragma unroll
    for (int fr = 0; fr < 4; fr++)
#pragma unroll
      for (int fc = 0; fc < 4; fc++)
        acc1[fr][fc] = __builtin_amdgcn_mfma_f32_16x16x32_bf16(wfr[fr], efr[fc], acc1[fr][fc], 0, 0, 0);
    cur ^= 1;
  }
  __syncthreads();   // all waves done reading Hsh edge-panel + Bsh

  issueW(g.W2s, 0, 0);
  // ---- psum regs -> Hsh (overwrites edge panel)
#pragma unroll
  for (int j = 0; j < 8; j++) {
    const int c = j * 4 + aq;
    *(uint4*)&Hsh[ppos(c, ar) * 8] = ps[j];
  }
  __syncthreads();   // psum visible; W2s(0) landed

  // ---- epilogue-1: h = silu(acc1 + psum); Hsh in-place; global h (PERMUTED); wp partials
  float pw[4] = {0.f, 0.f, 0.f, 0.f};
#pragma unroll
  for (int fr = 0; fr < 4; fr++) {
    const int nb = wave * 64 + fr * 16 + lhi * 4;
    const int kc = nb >> 3, off = nb & 7;
    uint2 wr = *(const uint2*)(g.w384 + nb);
    const __hip_bfloat16* w4 = (const __hip_bfloat16*)&wr;
#pragma unroll
    for (int fc = 0; fc < 4; fc++) {
      const int row = fc * 16 + l16;
      unsigned short* slot = &Hsh[ppos(kc, row) * 8 + off];
      uint2 pr = *(const uint2*)slot;
      const __hip_bfloat16* pp = (const __hip_bfloat16*)&pr;
      alignas(8) __hip_bfloat16 hb[4];
#pragma unroll
      for (int r = 0; r < 4; r++) {
        const float hv = siluf(acc1[fr][fc][r] + __bfloat162float(pp[r]));
        hb[r] = __float2bfloat16(hv);
        pw[fc] += hv * __bfloat162float(w4[r]);
      }
      *(uint2*)slot = *(const uint2*)hb;
      *(uint2*)(g.h_out + (size_t)Rk[row] * HIDc + nb) = *(const uint2*)hb;
    }
  }

  // ---- wp reduce
#pragma unroll
  for (int fc = 0; fc < 4; fc++) {
    pw[fc] += __shfl_xor(pw[fc], 16);
    pw[fc] += __shfl_xor(pw[fc], 32);
  }
  if (lane < 16) {
#pragma unroll
    for (int fc = 0; fc < 4; fc++) wps[wave][fc * 16 + lane] = pw[fc];
  }
  __syncthreads();   // h in Hsh + wps visible
  if (tid < 64) {
    const float s = wps[0][tid] + wps[1][tid] + wps[2][tid] + wps[3][tid];
    const float wpt = tanhf(s + g.b2L[384]);
    const int rk = Rk[tid];
#pragma unroll
    for (int c = 0; c < 3; c++)
      g.mp[(size_t)rk * 3 + c] = wpt * RnL[tid][c];
  }

  // ---- phase 2: out2 = h @ W2s. Barrier-free; Bsh[2] dbuf, counted vmcnt(4).
  f32x4 acc2[4][4] = {};
  cur = 0;
  for (int t = 0; t < T2; ++t) {
    if (t + 1 < T2) { issueW(g.W2s, t + 1, cur ^ 1); wait_vm4(); }
    else            { wait_vm0(); }
    bf16x8 afr[4], bfr[4];
#pragma unroll
    for (int f = 0; f < 4; f++) {
      afr[f] = *(const bf16x8*)&Hsh[ppos(t * 4 + lhi, f * 16 + l16) * 8];
      bfr[f] = *(const bf16x8*)&Bsh[cur][bpos(lhi, wave * 64 + f * 16 + l16) * 8];
    }
#pragma unroll
    for (int fr = 0; fr < 4; fr++)
#pragma unroll
      for (int fc = 0; fc < 4; fc++)
        acc2[fr][fc] = __builtin_amdgcn_mfma_f32_16x16x32_bf16(afr[fr], bfr[fc], acc2[fr][fc], 0, 0, 0);
    cur ^= 1;
  }

  // ---- epilogue-2: wv (PERMUTED) | e_new (edge order)
#pragma unroll
  for (int fr = 0; fr < 4; fr++) {
#pragma unroll
    for (int fc = 0; fc < 4; fc++) {
      const int n = wave * 64 + fc * 16 + l16;
#pragma unroll
      for (int r = 0; r < 4; r++) {
        const int lr = fr * 16 + lhi * 4 + r;
        const int row = row0 + lr;
        const float valf = acc2[fr][fc][r];
        if (n < 128) {
          g.wv_out[(size_t)Rk[lr] * 128 + n] = __float2bfloat16(valf + g.b2L[256 + n]);
        } else {
          const float sv = siluf(valf + g.b2L[257 + n]);
          g.e_bf_out[(size_t)row * ED + (n - 128)] = __float2bfloat16(sv);
          if (g.write_e_f32) g.e_f32_out[(size_t)row * ED + (n - 128)] = sv;
        }
      }
    }
  }
}

// ---- LayerNorm (layer 0 only).
__global__ __launch_bounds__(256) void ln_k(const float* __restrict__ s,
                                            const float* __restrict__ gl, const float* __restrict__ bl,
                                            __hip_bfloat16* __restrict__ s_ln) {
  const int wave = threadIdx.x >> 6, lane = threadIdx.x & 63;
  const int node = blockIdx.x * 4 + wave;
  const float* srow = s + (size_t)node * SD;
  float x[4], sum = 0.f, sq = 0.f;
#pragma unroll
  for (int i = 0; i < 4; i++) { x[i] = srow[lane * 4 + i]; sum += x[i]; sq += x[i] * x[i]; }
#pragma unroll
  for (int off = 1; off < 64; off <<= 1) { sum += __shfl_xor(sum, off); sq += __shfl_xor(sq, off); }
  const float mu = sum * (1.0f / SD);
  const float var = sq * (1.0f / SD) - mu * mu;
  const float rstd = rsqrtf(var + 1e-5f);
#pragma unroll
  for (int i = 0; i < 4; i++) {
    const int c = lane * 4 + i;
    s_ln[(size_t)node * SD + c] = __float2bfloat16(gl[c] * (x[i] - mu) * rstd + bl[c]);
  }
}

__global__ void cvt_e_k(const float* __restrict__ e, __hip_bfloat16* __restrict__ ebf) {
  const int i = blockIdx.x * blockDim.x + threadIdx.x;
  const float* p = e + (size_t)i * 8;
  alignas(16) __hip_bfloat16 t8[8];
#pragma unroll
  for (int j = 0; j < 8; j++) t8[j] = __float2bfloat16(p[j]);
  *(uint4*)(ebf + (size_t)i * 8) = *(const uint4*)t8;
}

__global__ void count_k(const int* __restrict__ tgt, int* __restrict__ rawcnt) {
  const int e = blockIdx.x * blockDim.x + threadIdx.x;
  if (e < NE) atomicAdd(&rawcnt[tgt[e]], 1);
}

__global__ __launch_bounds__(256) void scan_k(const int* __restrict__ rawcnt, int* __restrict__ off) {
  __shared__ int ts[256];
  const int tid = threadIdx.x;
  const int base = tid * 32;
  int local[32];
  int s = 0;
#pragma unroll
  for (int i = 0; i < 32; i++) { local[i] = s; s += rawcnt[base + i]; }
  ts[tid] = s;
  __syncthreads();
  if (tid == 0) {
    int acc = 0;
    for (int i = 0; i < 256; i++) { int t = ts[i]; ts[i] = acc; acc += t; }
    off[NN] = acc;
  }
  __syncthreads();
  const int pre = ts[tid];
#pragma unroll
  for (int i = 0; i < 32; i++) off[base + i] = pre + local[i];
}

__global__ void scatter_k(const int* __restrict__ tgt, const int* __restrict__ srcp,
                          const int* __restrict__ off,
                          int* __restrict__ cursor, int* __restrict__ rank, int* __restrict__ psrc) {
  const int e = blockIdx.x * blockDim.x + threadIdx.x;
  if (e < NE) {
    const int t = tgt[e];
    const int pos = off[t] + atomicAdd(&cursor[t], 1);
    rank[e] = pos;
    psrc[pos] = srcp[e];
  }
}

// ---- CSR aggregation: one block per node; sequential payload reads.
__global__ __launch_bounds__(256) void agg_k(const int* __restrict__ off, const int* __restrict__ psrc,
                                             const __hip_bfloat16* __restrict__ h,
                                             const __hip_bfloat16* __restrict__ wv,
                                             const float* __restrict__ mp,
                                             const float* __restrict__ rnp,
                                             const float* __restrict__ v_old,
                                             float* __restrict__ v_new,
                                             float* __restrict__ Hagg,
                                             float* __restrict__ p_o,
                                             int hasv) {
  const int n = blockIdx.x;
  const int c = threadIdx.x;
  const int e0 = off[n], e1 = off[n + 1];
  const int c3 = c >> 6, ln = c & 63;
  float hs = 0.f, vs = 0.f, ps = 0.f;
  int j = e0;
  for (; j + 2 <= e1; j += 2) {
    const float h0 = __bfloat162float(h[(size_t)j * HIDc + c]);
    const float h1 = __bfloat162float(h[(size_t)(j + 1) * HIDc + c]);
    hs += h0 + h1;
    if (c < 192) {
      const int s0 = psrc[j], s1 = psrc[j + 1];
      float m0 = __bfloat162float(wv[(size_t)j * 128 + 64 + ln]) * rnp[j * 3 + c3];
      float m1 = __bfloat162float(wv[(size_t)(j + 1) * 128 + 64 + ln]) * rnp[(j + 1) * 3 + c3];
      if (hasv) {
        m0 += __bfloat162float(wv[(size_t)j * 128 + ln]) * v_old[(size_t)s0 * 192 + c];
        m1 += __bfloat162float(wv[(size_t)(j + 1) * 128 + ln]) * v_old[(size_t)s1 * 192 + c];
      }
      vs += m0 + m1;
    } else if (c < 195) {
      ps += mp[j * 3 + (c - 192)] + mp[(j + 1) * 3 + (c - 192)];
    }
  }
  for (; j < e1; j++) {
    hs += __bfloat162float(h[(size_t)j * HIDc + c]);
    if (c < 192) {
      float mv = __bfloat162float(wv[(size_t)j * 128 + 64 + ln]) * rnp[j * 3 + c3];
      if (hasv) mv += __bfloat162float(wv[(size_t)j * 128 + ln]) * v_old[(size_t)psrc[j] * 192 + c];
      vs += mv;
    } else if (c < 195) {
      ps += mp[j * 3 + (c - 192)];
    }
  }
  Hagg[(size_t)n * HIDc + c] = hs;
  const float inv = 1.0f / fmaxf((float)(e1 - e0), 1.0f);
  if (c < 192)      v_new[(size_t)n * 192 + c] = v_old[(size_t)n * 192 + c] + vs * inv;
  else if (c < 195) p_o[n * 3 + (c - 192)]    += ps * inv;
}

__global__ void zero_k(float* __restrict__ ptr, int n) {
  const int i = blockIdx.x * blockDim.x + threadIdx.x;
  if (i < n) ptr[i] = 0.f;
}

// ---- weight prep -> swizzled streams
__global__ void prep_w1abs_k(const float* __restrict__ W1, __hip_bfloat16* __restrict__ W1aS,
                             __hip_bfloat16* __restrict__ W1bS) {
  const int idx = blockIdx.x * blockDim.x + threadIdx.x;
  if (idx >= NL * T2 * 1024) return;
  const int p = idx & 1023, t = (idx >> 10) % T2, l = idx / (T2 * 1024);
  const int kc = p >> 8, n = (p & 255) ^ swz(kc);
  alignas(16) __hip_bfloat16 a8[8], b8[8];
#pragma unroll
  for (int j = 0; j < 8; j++) {
    const int k = t * 32 + kc * 8 + j;
    a8[j] = __float2bfloat16(W1[((size_t)l * DINc + k) * HIDc + n]);
    b8[j] = __float2bfloat16(W1[((size_t)l * DINc + 256 + k) * HIDc + n]);
  }
  *(uint4*)(W1aS + (size_t)idx * 8) = *(const uint4*)a8;
  *(uint4*)(W1bS + (size_t)idx * 8) = *(const uint4*)b8;
}

__global__ void prep_w1es_k(const float* __restrict__ W1, __hip_bfloat16* __restrict__ W1eS) {
  const int idx = blockIdx.x * blockDim.x + threadIdx.x;
  if (idx >= NL * TE * 1024) return;
  const int p = idx & 1023, t = (idx >> 10) % TE, l = idx / (TE * 1024);
  const int kc = p >> 8, n = (p & 255) ^ swz(kc);
  alignas(16) __hip_bfloat16 e8[8];
#pragma unroll
  for (int j = 0; j < 8; j++) {
    const int k = t * 32 + kc * 8 + j;
    const int row = (k < 128) ? (512 + k) : ((k < 132) ? (640 + (k - 128)) : -1);
    e8[j] = __float2bfloat16(row >= 0 ? W1[((size_t)l * DINc + row) * HIDc + n] : 0.f);
  }
  *(uint4*)(W1eS + (size_t)idx * 8) = *(const uint4*)e8;
}

__global__ void prep_w2s_k(const float* __restrict__ W2, __hip_bfloat16* __restrict__ W2sS,
                           __hip_bfloat16* __restrict__ W2aS) {
  const int idx = blockIdx.x * blockDim.x + threadIdx.x;
  if (idx >= NL * T2 * 1024) return;
  const int p = idx & 1023, t = (idx >> 10) & 7, l = idx >> 13;
  const int kc = p >> 8, n = (p & 255) ^ swz(kc);
  const float* W2l = W2 + (size_t)l * HIDc * DOUTc;
  const int cs = (n < 128) ? (256 + n) : (257 + n);
  alignas(16) __hip_bfloat16 s8[8], a8[8];
#pragma unroll
  for (int j = 0; j < 8; j++) {
    const int k = t * 32 + kc * 8 + j;
    s8[j] = __float2bfloat16(W2l[(size_t)k * DOUTc + cs]);
    a8[j] = __float2bfloat16(W2l[(size_t)k * DOUTc + n]);
  }
  *(uint4*)(W2sS + (size_t)idx * 8) = *(const uint4*)s8;
  *(uint4*)(W2aS + (size_t)idx * 8) = *(const uint4*)a8;
}

__global__ void prep_uts_k(const float* __restrict__ U1, const float* __restrict__ U2,
                           __hip_bfloat16* __restrict__ U1S, __hip_bfloat16* __restrict__ U2S) {
  const int idx = blockIdx.x * blockDim.x + threadIdx.x;
  if (idx >= NL * T2 * 1024) return;
  const int p = idx & 1023, t = (idx >> 10) & 7, l = idx >> 13;
  const int kc = p >> 8, n = (p & 255) ^ swz(kc);
  alignas(16) __hip_bfloat16 u1[8], u2[8];
#pragma unroll
  for (int j = 0; j < 8; j++) {
    const int k = t * 32 + kc * 8 + j;
    u1[j] = __float2bfloat16(U1[((size_t)l * HIDc + k) * HIDc + n]);
    u2[j] = __float2bfloat16(U2[((size_t)l * HIDc + k) * HIDc + n]);
  }
  *(uint4*)(U1S + (size_t)idx * 8) = *(const uint4*)u1;
  *(uint4*)(U2S + (size_t)idx * 8) = *(const uint4*)u2;
}

__global__ void prep_w384_k(const float* __restrict__ W2, __hip_bfloat16* __restrict__ w384) {
  const int idx = blockIdx.x * blockDim.x + threadIdx.x;
  if (idx >= NL * HIDc) return;
  const int k = idx & 255, l = idx >> 8;
  w384[idx] = __float2bfloat16(W2[((size_t)l * HIDc + k) * DOUTc + 384]);
}

}  // namespace

extern "C" void kernel_launch(void* const* d_in, const int* in_sizes, int n_in,
                              void* d_out, int out_size, void* d_ws, size_t ws_size,
                              hipStream_t stream) {
  (void)in_sizes; (void)n_in; (void)out_size; (void)ws_size;
  const float* s_in = (const float*)d_in[0];
  const float* v_in = (const float*)d_in[1];
  const float* p_in = (const float*)d_in[2];
  const float* e_in = (const float*)d_in[3];
  const int*   ei   = (const int*)d_in[4];
  const float* ln_g = (const float*)d_in[5];
  const float* ln_b = (const float*)d_in[6];
  const float* W1   = (const float*)d_in[7];
  const float* b1   = (const float*)d_in[8];
  const float* W2   = (const float*)d_in[9];
  const float* b2   = (const float*)d_in[10];
  const float* U1   = (const float*)d_in[11];
  const float* bU1  = (const float*)d_in[12];
  const float* U2   = (const float*)d_in[13];
  const float* bU2  = (const float*)d_in[14];

  float* s_o = (float*)d_out;
  float* v_o = s_o + (size_t)NN * SD;
  float* e_o = v_o + (size_t)NN * 192;
  float* p_o = e_o + (size_t)NE * ED;

  const int* srcp = ei;
  const int* tgtp = ei + NE;

  char* wp = (char*)d_ws;
  auto alloc = [&](size_t bytes) -> char* {
    char* r = wp; wp += (bytes + 255) & ~(size_t)255; return r;
  };
  __hip_bfloat16* s_ln = (__hip_bfloat16*)alloc((size_t)NN * SD * 2);
  __hip_bfloat16* hbuf = (__hip_bfloat16*)alloc((size_t)NE * HIDc * 2);
  __hip_bfloat16* ebf  = (__hip_bfloat16*)alloc((size_t)NE * ED * 2);
  __hip_bfloat16* wvbuf= (__hip_bfloat16*)alloc((size_t)NE * 128 * 2);
  __hip_bfloat16* p1buf= (__hip_bfloat16*)alloc((size_t)NN * SD * 2);
  __hip_bfloat16* p2buf= (__hip_bfloat16*)alloc((size_t)NN * SD * 2);
  float* rnpbuf= (float*)alloc((size_t)NE * 3 * 4);
  float* Hagg  = (float*)alloc((size_t)NN * SD * 4);
  float* vprev = (float*)alloc((size_t)NN * 192 * 4);
  float* mpbuf = (float*)alloc((size_t)NE * 3 * 4);
  float* zerobias = (float*)alloc(256 * 4);
  int*   rawcnt= (int*)alloc((size_t)NN * 4);
  int*   offb  = (int*)alloc((size_t)(NN + 1) * 4);
  int*   cursor= (int*)alloc((size_t)NN * 4);
  int*   rankb = (int*)alloc((size_t)NE * 4);
  int*   psrcb = (int*)alloc((size_t)NE * 4);
  __hip_bfloat16* W1aS = (__hip_bfloat16*)alloc((size_t)NL * T2 * 1024 * 8 * 2);
  __hip_bfloat16* W1bS = (__hip_bfloat16*)alloc((size_t)NL * T2 * 1024 * 8 * 2);
  __hip_bfloat16* W1eS = (__hip_bfloat16*)alloc((size_t)NL * TE * 1024 * 8 * 2);
  __hip_bfloat16* W2sS = (__hip_bfloat16*)alloc((size_t)NL * T2 * 1024 * 8 * 2);
  __hip_bfloat16* W2aS = (__hip_bfloat16*)alloc((size_t)NL * T2 * 1024 * 8 * 2);
  __hip_bfloat16* U1S  = (__hip_bfloat16*)alloc((size_t)NL * T2 * 1024 * 8 * 2);
  __hip_bfloat16* U2S  = (__hip_bfloat16*)alloc((size_t)NL * T2 * 1024 * 8 * 2);
  __hip_bfloat16* w384 = (__hip_bfloat16*)alloc((size_t)NL * HIDc * 2);

  hipMemcpyAsync(s_o, s_in, (size_t)NN * SD * 4, hipMemcpyDeviceToDevice, stream);
  hipMemcpyAsync(vprev, v_in, (size_t)NN * 192 * 4, hipMemcpyDeviceToDevice, stream);
  hipMemcpyAsync(p_o, p_in, (size_t)NN * 3 * 4, hipMemcpyDeviceToDevice, stream);

  prep_w1abs_k<<<(NL * T2 * 1024 + 255) / 256, 256, 0, stream>>>(W1, W1aS, W1bS);
  prep_w1es_k<<<(NL * TE * 1024 + 255) / 256, 256, 0, stream>>>(W1, W1eS);
  prep_w2s_k<<<(NL * T2 * 1024 + 255) / 256, 256, 0, stream>>>(W2, W2sS, W2aS);
  prep_uts_k<<<(NL * T2 * 1024 + 255) / 256, 256, 0, stream>>>(U1, U2, U1S, U2S);
  prep_w384_k<<<(NL * HIDc + 255) / 256, 256, 0, stream>>>(W2, w384);
  cvt_e_k<<<NE * ED / 8 / 256, 256, 0, stream>>>(e_in, ebf);
  zero_k<<<1, 256, 0, stream>>>(zerobias, 256);

  // ---- CSR build (once; edge_index layer-invariant)
  zero_k<<<(NN + 255) / 256, 256, 0, stream>>>((float*)rawcnt, NN);
  zero_k<<<(NN + 255) / 256, 256, 0, stream>>>((float*)cursor, NN);
  count_k<<<NE / 256, 256, 0, stream>>>(tgtp, rawcnt);
  scan_k<<<1, 256, 0, stream>>>(rawcnt, offb);
  scatter_k<<<NE / 256, 256, 0, stream>>>(tgtp, srcp, offb, cursor, rankb, psrcb);

  // ---- layer 0: LN + P1/P2 (subsequent layers fold these into node3)
  ln_k<<<NN / 4, 256, 0, stream>>>(s_o, ln_g, ln_b, s_ln);
  GemmArgs gp{};
  gp.Wt = W1aS; gp.bias = b1; gp.bf_out = p1buf;
  gp.Wtb = W1bS; gp.biasb = zerobias; gp.bf_outb = p2buf;
  gp.Abf = s_ln; gp.dual = 1;
  gemm_k<256, 64><<<2 * NN / 64, 256, 0, stream>>>(gp);

  for (int l = 0; l < NL; l++) {
    // fused edge kernel: attrs + h + out2 (h/wv/mp/rnp written at rank[e])
    FusedArgs gf{};
    gf.W1e = W1eS + (size_t)l * TE * 1024 * 8;
    gf.W2s = W2sS + (size_t)l * T2 * 1024 * 8;
    gf.b2L = b2 + l * DOUTc;
    gf.src = srcp; gf.tgt = tgtp; gf.rank = rankb;
    gf.pos = p_o; gf.e_bf = ebf;
    gf.p1 = p1buf; gf.p2 = p2buf; gf.w384 = w384 + l * HIDc;
    gf.rnp = rnpbuf; gf.mp = mpbuf;
    gf.h_out = hbuf; gf.wv_out = wvbuf; gf.e_bf_out = ebf; gf.e_f32_out = e_o;
    gf.write_e_f32 = (l == NL - 1) ? 1 : 0;
    fused_k<<<NE / 64, 256, 0, stream>>>(gf);

    // v ping-pong: 5 layers -> final write lands in v_o.
    const float* vold = (l & 1) ? (const float*)v_o : (const float*)vprev;
    float* vnew = (l & 1) ? vprev : v_o;
    agg_k<<<NN, 256, 0, stream>>>(offb, psrcb, hbuf, wvbuf, mpbuf, rnpbuf,
                                  vold, vnew, Hagg, p_o, (l > 0) ? 1 : 0);

    // fused node MLP (+ next-layer LN/P1/P2 when l<4)
    Node3Args gn{};
    gn.W2a = W2aS + (size_t)l * T2 * 1024 * 8;
    gn.U1s = U1S + (size_t)l * T2 * 1024 * 8;
    gn.U2s = U2S + (size_t)l * T2 * 1024 * 8;
    gn.b2L = b2 + l * DOUTc; gn.bU1 = bU1 + l * HIDc; gn.bU2 = bU2 + l * HIDc;
    gn.Hagg = Hagg; gn.rawcnt = rawcnt; gn.s_out = s_o;
    if (l < NL - 1) {
      gn.W1an = W1aS + (size_t)(l + 1) * T2 * 1024 * 8;
      gn.W1bn = W1bS + (size_t)(l + 1) * T2 * 1024 * 8;
      gn.b1n = b1 + (l + 1) * HIDc;
      gn.lng = ln_g + (l + 1) * SD; gn.lnb = ln_b + (l + 1) * SD;
      gn.p1 = p1buf; gn.p2 = p2buf;
      node3_k<0><<<NN / 32, 256, 0, stream>>>(gn);
    } else {
      node3_k<1><<<NN / 32, 256, 0, stream>>>(gn);
    }
  }
}

// Round 15
// 1018.499 us; speedup vs baseline: 1.3787x; 1.3787x over previous
//
#include <hip/hip_runtime.h>
#include <hip/hip_bf16.h>

namespace {

constexpr int NN   = 8192;    // nodes
constexpr int NE   = 131072;  // edges
constexpr int SD   = 256;     // SDIM
constexpr int ED   = 128;     // EDIM
constexpr int NL   = 5;       // layers
constexpr int DINc = 644;     // 2*SD + ED + 4
constexpr int KE   = 160;     // edge-GEMM K: 128 e + 4 scalars + pad
constexpr int TE   = 5;       // KE/32
constexpr int T2   = 8;       // 256/32
constexpr int DOUTc= 513;
constexpr int HIDc = 256;

typedef __bf16 bf16x8 __attribute__((ext_vector_type(8)));
typedef float  f32x4  __attribute__((ext_vector_type(4)));

__device__ __forceinline__ float siluf(float x) { return x / (1.0f + __expf(-x)); }

// async global->LDS, 16B/lane. LDS dest is wave-uniform base (+lane*16 in HW).
__device__ __forceinline__ void gl_lds16(const void* gsrc, void* lds_uniform_base) {
  __builtin_amdgcn_global_load_lds(
      (const __attribute__((address_space(1))) unsigned int*)gsrc,
      (__attribute__((address_space(3))) unsigned int*)lds_uniform_base, 16, 0, 0);
}

__device__ __forceinline__ void wait_vm4() {
  asm volatile("s_waitcnt vmcnt(4)" ::: "memory");
  __builtin_amdgcn_sched_barrier(0);
}
__device__ __forceinline__ void wait_vm0() {
  asm volatile("s_waitcnt vmcnt(0)" ::: "memory");
  __builtin_amdgcn_sched_barrier(0);
}

// bank-group swizzle: (5x)&7 is a permutation on 0..7.
__device__ __host__ __forceinline__ int swz(int kc) { return (kc * 5) & 7; }
__device__ __forceinline__ int apos(int kc, int row) { return kc * 64  + (row ^ swz(kc)); }
__device__ __forceinline__ int bpos(int kc, int n)   { return kc * 256 + (n   ^ swz(kc)); }

enum { SRC_BF16 = 1 };

struct GemmArgs {
  const __hip_bfloat16* Wt;     // swizzled B stream
  const float* bias;
  const __hip_bfloat16* Abf;
  __hip_bfloat16* bf_out;
  const __hip_bfloat16* Wtb;    // dual second half
  const float* biasb;
  __hip_bfloat16* bf_outb;
  int dual;
};

__device__ __forceinline__ uint4 cvt8f(const float* p) {
  alignas(16) __hip_bfloat16 t8[8];
#pragma unroll
  for (int i = 0; i < 8; i++) t8[i] = __float2bfloat16(p[i]);
  return *(const uint4*)t8;
}

// Layer-0 P1/P2: BM=64, BN=256, dual-launch. A-panel staged once; barrier-free loop.
template<int KTOT, int BM>
__global__ __launch_bounds__(256) void gemm_k(GemmArgs g) {
  constexpr int T = KTOT / 32;
  constexpr int NC = KTOT / 8;
  constexpr int RPT = 256 / BM;
  constexpr int RMASK = RPT - 1;
  __shared__ alignas(16) unsigned short Apan[NC * BM * 8];
  __shared__ alignas(16) unsigned short Bsh[2][4 * 256 * 8];
  const int tid = threadIdx.x, lane = tid & 63, wave = tid >> 6;
  const int l16 = lane & 15, lhi = lane >> 4;
  const __hip_bfloat16* wtp = g.Wt;
  const float* biasp = g.bias;
  __hip_bfloat16* outp = g.bf_out;
  int blk = blockIdx.x;
  {
    const int half = gridDim.x >> 1;
    if (g.dual && blk >= half) { blk -= half; wtp = g.Wtb; biasp = g.biasb; outp = g.bf_outb; }
  }
  const int row0 = blk * BM;
  const int ar = tid / RPT, aq = tid % RPT;
  const int arow = row0 + ar;
  f32x4 acc[BM / 16][4] = {};

  auto issueB = [&](int t, int buf) {
    const __hip_bfloat16* src = wtp + (size_t)t * 1024 * 8;
    unsigned short* dst = &Bsh[buf][0];
#pragma unroll
    for (int i = 0; i < 4; i++)
      gl_lds16(src + (size_t)(i * 256 + wave * 64 + lane) * 8, dst + (i * 256 + wave * 64) * 8);
  };

  issueB(0, 0);
#pragma unroll
  for (int j = 0; j < NC / RPT; j++) {
    const int c = j * RPT + aq;
    uint4 o = *(const uint4*)(g.Abf + (size_t)arow * KTOT + c * 8);
    *(uint4*)&Apan[(c * BM + (ar ^ swz(aq))) * 8] = o;
  }
  __syncthreads();

  int cur = 0;
  for (int t = 0; t < T; ++t) {
    if (t + 1 < T) { issueB(t + 1, cur ^ 1); wait_vm4(); }
    else           { wait_vm0(); }
    bf16x8 bfr[4];
#pragma unroll
    for (int f = 0; f < 4; f++)
      bfr[f] = *(const bf16x8*)&Bsh[cur][bpos(lhi, wave * 64 + f * 16 + l16) * 8];
#pragma unroll
    for (int fr = 0; fr < BM / 16; fr++) {
      const int kc = t * 4 + lhi;
      const bf16x8 afr = *(const bf16x8*)&Apan[(kc * BM + ((fr * 16 + l16) ^ swz(kc & RMASK))) * 8];
#pragma unroll
      for (int fc = 0; fc < 4; fc++)
        acc[fr][fc] = __builtin_amdgcn_mfma_f32_16x16x32_bf16(afr, bfr[fc], acc[fr][fc], 0, 0, 0);
    }
    cur ^= 1;
  }

#pragma unroll
  for (int fr = 0; fr < BM / 16; fr++) {
#pragma unroll
    for (int fc = 0; fc < 4; fc++) {
      const int n = wave * 64 + fc * 16 + l16;
#pragma unroll
      for (int r = 0; r < 4; r++) {
        const int row = row0 + fr * 16 + lhi * 4 + r;
        outp[(size_t)row * HIDc + n] = __float2bfloat16(acc[fr][fc][r] + biasp[n]);
      }
    }
  }
}

// ==== fused node kernel: s-update + node MLP + next-layer LN + P1/P2 ====
struct Node3Args {
  const __hip_bfloat16* W2a;
  const __hip_bfloat16* U1s;
  const __hip_bfloat16* U2s;
  const __hip_bfloat16* W1an;   // next layer streams
  const __hip_bfloat16* W1bn;
  const float* b2L;
  const float* bU1;
  const float* bU2;
  const float* b1n;             // next layer b1
  const float* lng;             // next layer ln params
  const float* lnb;
  const float* Hagg;
  const int* rawcnt;
  float* s_out;
  __hip_bfloat16* p1;
  __hip_bfloat16* p2;
};

template<int LAST>
__global__ __launch_bounds__(256) void node3_k(Node3Args g) {
  constexpr int BM = 32, RPT = 8, NC = 32, T = 8;
  __shared__ alignas(16) unsigned short Apan[NC * BM * 8];      // 16 KB
  __shared__ alignas(16) unsigned short Bsh[2][4 * 256 * 8];    // 32 KB
  __shared__ float red[2][4][32];
  const int tid = threadIdx.x, lane = tid & 63, wave = tid >> 6;
  const int l16 = lane & 15, lhi = lane >> 4;
  const int row0 = blockIdx.x * BM;
  const int ar = tid >> 3, aq = tid & 7;

  auto issueB = [&](const __hip_bfloat16* W, int t, int buf) {
    const __hip_bfloat16* src = W + (size_t)t * 1024 * 8;
    unsigned short* dst = &Bsh[buf][0];
#pragma unroll
    for (int i = 0; i < 4; i++)
      gl_lds16(src + (size_t)(i * 256 + wave * 64 + lane) * 8, dst + (i * 256 + wave * 64) * 8);
  };

  f32x4 acc[4][2];   // SWAPPED: acc[n-blk][row-blk], D[n][row]
  auto kloop = [&](const __hip_bfloat16* W) {
#pragma unroll
    for (int i = 0; i < 4; i++)
#pragma unroll
      for (int j = 0; j < 2; j++) acc[i][j] = f32x4{0.f, 0.f, 0.f, 0.f};
    int cur = 0;
    for (int t = 0; t < T; ++t) {
      if (t + 1 < T) { issueB(W, t + 1, cur ^ 1); wait_vm4(); }
      else           { wait_vm0(); }
      bf16x8 wfr[4], afr[2];
#pragma unroll
      for (int f = 0; f < 4; f++)
        wfr[f] = *(const bf16x8*)&Bsh[cur][bpos(lhi, wave * 64 + f * 16 + l16) * 8];
#pragma unroll
      for (int f = 0; f < 2; f++) {
        const int kc = t * 4 + lhi;
        afr[f] = *(const bf16x8*)&Apan[(kc * BM + ((f * 16 + l16) ^ swz(kc & 7))) * 8];
      }
#pragma unroll
      for (int fr = 0; fr < 4; fr++)
#pragma unroll
        for (int fc = 0; fc < 2; fc++)
          acc[fr][fc] = __builtin_amdgcn_mfma_f32_16x16x32_bf16(wfr[fr], afr[fc], acc[fr][fc], 0, 0, 0);
      cur ^= 1;
    }
  };

  // ---- stage Hagg panel (f32 -> bf16)
  issueB(g.W2a, 0, 0);
#pragma unroll
  for (int j = 0; j < NC / RPT; j++) {
    const int c = j * RPT + aq;
    uint4 o = cvt8f(g.Hagg + (size_t)(row0 + ar) * SD + c * 8);
    *(uint4*)&Apan[(c * BM + (ar ^ swz(aq))) * 8] = o;
  }
  __syncthreads();

  // ---- step A: Hagg @ W2a -> s1
  kloop(g.W2a);
  __syncthreads();
  if constexpr (!LAST) issueB(g.U1s, 0, 0);

#pragma unroll
  for (int fr = 0; fr < 4; fr++) {
    const int nb = wave * 64 + fr * 16 + lhi * 4;
    const int kc = nb >> 3, off = nb & 7;
    const f32x4 b4 = *(const f32x4*)(g.b2L + nb);
#pragma unroll
    for (int fc = 0; fc < 2; fc++) {
      const int row = fc * 16 + l16;
      const float rc = (float)g.rawcnt[row0 + row];
      float* sp = g.s_out + (size_t)(row0 + row) * SD + nb;
      f32x4 sold = *(const f32x4*)sp;
      alignas(8) __hip_bfloat16 hb[4];
      f32x4 s1;
#pragma unroll
      for (int r = 0; r < 4; r++) {
        s1[r] = sold[r] + acc[fr][fc][r] + rc * b4[r];
        hb[r] = __float2bfloat16(s1[r]);
      }
      *(f32x4*)sp = s1;
      if constexpr (!LAST)
        *(uint2*)&Apan[(kc * BM + (row ^ swz(kc & 7))) * 8 + off] = *(const uint2*)hb;
    }
  }
  if constexpr (LAST) return;

  __syncthreads();   // s1 panel visible; U1(0) landed

  // ---- step B: t = silu(s1@U1 + bU1) -> Apan
  kloop(g.U1s);
  __syncthreads();
  issueB(g.U2s, 0, 0);
#pragma unroll
  for (int fr = 0; fr < 4; fr++) {
    const int nb = wave * 64 + fr * 16 + lhi * 4;
    const int kc = nb >> 3, off = nb & 7;
    const f32x4 b4 = *(const f32x4*)(g.bU1 + nb);
#pragma unroll
    for (int fc = 0; fc < 2; fc++) {
      const int row = fc * 16 + l16;
      alignas(8) __hip_bfloat16 hb[4];
#pragma unroll
      for (int r = 0; r < 4; r++)
        hb[r] = __float2bfloat16(siluf(acc[fr][fc][r] + b4[r]));
      *(uint2*)&Apan[(kc * BM + (row ^ swz(kc & 7))) * 8 + off] = *(const uint2*)hb;
    }
  }
  __syncthreads();   // t panel visible; U2(0) landed

  // ---- step C: s2 = s1 + t@U2 + bU2 (s_o RMW); row stats for LN
  kloop(g.U2s);
  float psum[2] = {0.f, 0.f}, psq[2] = {0.f, 0.f};
#pragma unroll
  for (int fr = 0; fr < 4; fr++) {
    const int nb = wave * 64 + fr * 16 + lhi * 4;
    const f32x4 b4 = *(const f32x4*)(g.bU2 + nb);
#pragma unroll
    for (int fc = 0; fc < 2; fc++) {
      const int row = fc * 16 + l16;
      float* sp = g.s_out + (size_t)(row0 + row) * SD + nb;
      f32x4 sv = *(const f32x4*)sp;
#pragma unroll
      for (int r = 0; r < 4; r++) {
        sv[r] += acc[fr][fc][r] + b4[r];
        psum[fc] += sv[r];
        psq[fc] += sv[r] * sv[r];
      }
      *(f32x4*)sp = sv;
      acc[fr][fc] = sv;   // keep s2 in regs
    }
  }
#pragma unroll
  for (int fc = 0; fc < 2; fc++) {
    psum[fc] += __shfl_xor(psum[fc], 16); psum[fc] += __shfl_xor(psum[fc], 32);
    psq[fc]  += __shfl_xor(psq[fc], 16);  psq[fc]  += __shfl_xor(psq[fc], 32);
  }
  if (lane < 16) {
    red[0][wave][lane] = psum[0]; red[0][wave][16 + lane] = psum[1];
    red[1][wave][lane] = psq[0];  red[1][wave][16 + lane] = psq[1];
  }
  __syncthreads();   // red visible; all waves done reading Apan (t-panel)

  float mu2[2], rs2[2];
#pragma unroll
  for (int fc = 0; fc < 2; fc++) {
    const int ri = fc * 16 + l16;
    const float S = red[0][0][ri] + red[0][1][ri] + red[0][2][ri] + red[0][3][ri];
    const float Q = red[1][0][ri] + red[1][1][ri] + red[1][2][ri] + red[1][3][ri];
    const float mu = S * (1.0f / SD);
    const float var = Q * (1.0f / SD) - mu * mu;
    mu2[fc] = mu; rs2[fc] = rsqrtf(var + 1e-5f);
  }
  // ---- s_ln = LN_{l+1}(s2) -> Apan
#pragma unroll
  for (int fr = 0; fr < 4; fr++) {
    const int nb = wave * 64 + fr * 16 + lhi * 4;
    const int kc = nb >> 3, off = nb & 7;
    const f32x4 g4 = *(const f32x4*)(g.lng + nb);
    const f32x4 bb4 = *(const f32x4*)(g.lnb + nb);
#pragma unroll
    for (int fc = 0; fc < 2; fc++) {
      const int row = fc * 16 + l16;
      alignas(8) __hip_bfloat16 hb[4];
#pragma unroll
      for (int r = 0; r < 4; r++)
        hb[r] = __float2bfloat16(g4[r] * (acc[fr][fc][r] - mu2[fc]) * rs2[fc] + bb4[r]);
      *(uint2*)&Apan[(kc * BM + (row ^ swz(kc & 7))) * 8 + off] = *(const uint2*)hb;
    }
  }
  issueB(g.W1an, 0, 0);
  __syncthreads();   // s_ln panel visible; W1a(0) landed

  // ---- step D: P1 = s_ln @ W1a_{l+1} + b1_{l+1}
  kloop(g.W1an);
#pragma unroll
  for (int fr = 0; fr < 4; fr++) {
    const int nb = wave * 64 + fr * 16 + lhi * 4;
    const f32x4 b4 = *(const f32x4*)(g.b1n + nb);
#pragma unroll
    for (int fc = 0; fc < 2; fc++) {
      const int row = fc * 16 + l16;
      alignas(8) __hip_bfloat16 hb[4];
#pragma unroll
      for (int r = 0; r < 4; r++)
        hb[r] = __float2bfloat16(acc[fr][fc][r] + b4[r]);
      *(uint2*)(g.p1 + (size_t)(row0 + row) * SD + nb) = *(const uint2*)hb;
    }
  }
  // ---- step E: P2 = s_ln @ W1b_{l+1}
  issueB(g.W1bn, 0, 0);
  kloop(g.W1bn);
#pragma unroll
  for (int fr = 0; fr < 4; fr++) {
    const int nb = wave * 64 + fr * 16 + lhi * 4;
#pragma unroll
    for (int fc = 0; fc < 2; fc++) {
      const int row = fc * 16 + l16;
      alignas(8) __hip_bfloat16 hb[4];
#pragma unroll
      for (int r = 0; r < 4; r++)
        hb[r] = __float2bfloat16(acc[fr][fc][r]);
      *(uint2*)(g.p2 + (size_t)(row0 + row) * SD + nb) = *(const uint2*)hb;
    }
  }
}

// ==== fused edge kernel (R8 structure + in-kernel edge attrs) ====
struct FusedArgs {
  const __hip_bfloat16* W1e;
  const __hip_bfloat16* W2s;
  const float* b2L;
  const int* src; const int* tgt;
  const int* rank;
  const float* pos;             // p_o [NN][3]
  const __hip_bfloat16* e_bf;
  const __hip_bfloat16* p1;
  const __hip_bfloat16* p2;
  const __hip_bfloat16* w384;
  float* rnp;                   // [NE][3] out, PERMUTED
  float* mp;                    // [NE][3] out, PERMUTED
  __hip_bfloat16* h_out;        // [NE][256], PERMUTED
  __hip_bfloat16* wv_out;       // [NE][128], PERMUTED
  __hip_bfloat16* e_bf_out;     // [NE][128], edge order
  float* e_f32_out;             // d_out e region, edge order
  int write_e_f32;
};

__global__ __launch_bounds__(256) void fused_k(FusedArgs g) {
  __shared__ alignas(16) unsigned short Ash[4 * 64 * 8];        // 4 KB (edge A)
  __shared__ alignas(16) unsigned short Bsh[2][4 * 256 * 8];    // 32 KB (W stream dbuf)
  __shared__ alignas(16) unsigned short Hsh[32 * 64 * 8];       // 32 KB (psum -> h)
  __shared__ float wps[4][64];
  __shared__ float RnL[64][3];
  __shared__ unsigned int EdL[64][2];
  __shared__ int Rk[64];
  const int tid = threadIdx.x, lane = tid & 63, wave = tid >> 6;
  const int l16 = lane & 15, lhi = lane >> 4;
  const int row0 = blockIdx.x * 64;
  const int ar = tid >> 2, aq = tid & 3;
  const int arow = row0 + ar;
  const int sn = g.src[arow], tn = g.tgt[arow];

  auto issueW = [&](const __hip_bfloat16* W, int t, int buf) {
    const __hip_bfloat16* src = W + (size_t)t * 1024 * 8;
    unsigned short* dst = &Bsh[buf][0];
#pragma unroll
    for (int i = 0; i < 4; i++)
      gl_lds16(src + (size_t)(i * 256 + wave * 64 + lane) * 8, dst + (i * 256 + wave * 64) * 8);
  };
  auto loadA = [&](int t, uint4& o) {
    if (t < 4) {
      o = *(const uint4*)(g.e_bf + (size_t)arow * ED + t * 32 + aq * 8);
    } else {
      o.x = o.y = o.z = o.w = 0;
      if (aq == 0) { o.x = EdL[ar][0]; o.y = EdL[ar][1]; }
    }
  };

  uint4 a;
  loadA(0, a);
  issueW(g.W1e, 0, 0);

  // ---- in-kernel edge attrs: d,a,pn -> EdL; rn -> RnL + rnp
  if (tid < 64) {
    const int e = row0 + tid;
    const int rk = g.rank[e];
    Rk[tid] = rk;
    const int s_ = g.src[e], t_ = g.tgt[e];
    const float sx = g.pos[s_ * 3], sy = g.pos[s_ * 3 + 1], sz = g.pos[s_ * 3 + 2];
    const float tx = g.pos[t_ * 3], ty = g.pos[t_ * 3 + 1], tz = g.pos[t_ * 3 + 2];
    const float rx = tx - sx, ry = ty - sy, rz = tz - sz;
    const float av = tx * sx + ty * sy + tz * sz;
    const float rr = rx * rx + ry * ry + rz * rz;
    const float d = sqrtf(fmaxf(rr, 1e-6f));
    const float inv = 1.0f / (1.0f + d);
    const float r0 = rx * inv, r1 = ry * inv, r2 = rz * inv;
    RnL[tid][0] = r0; RnL[tid][1] = r1; RnL[tid][2] = r2;
    g.rnp[rk * 3] = r0; g.rnp[rk * 3 + 1] = r1; g.rnp[rk * 3 + 2] = r2;
    alignas(8) __hip_bfloat16 q[4];
    q[0] = __float2bfloat16(d);
    q[1] = __float2bfloat16(av);
    q[2] = __float2bfloat16(sqrtf(sx * sx + sy * sy + sz * sz));
    q[3] = __float2bfloat16(sqrtf(tx * tx + ty * ty + tz * tz));
    EdL[tid][0] = ((const unsigned*)q)[0];
    EdL[tid][1] = ((const unsigned*)q)[1];
  }

  // ---- stage Psum = P1[sn] + P2[tn] into Hsh
#pragma unroll
  for (int j = 0; j < 8; j++) {
    const int c = j * 4 + aq;
    uint4 r1 = *(const uint4*)(g.p1 + (size_t)sn * SD + c * 8);
    uint4 r2 = *(const uint4*)(g.p2 + (size_t)tn * SD + c * 8);
    const __hip_bfloat16* h1 = (const __hip_bfloat16*)&r1;
    const __hip_bfloat16* h2 = (const __hip_bfloat16*)&r2;
    alignas(16) __hip_bfloat16 o8[8];
#pragma unroll
    for (int m = 0; m < 8; m++)
      o8[m] = __float2bfloat16(__bfloat162float(h1[m]) + __bfloat162float(h2[m]));
    *(uint4*)&Hsh[(c * 64 + (ar ^ swz(aq))) * 8] = *(const uint4*)o8;
  }

  // ---- phase 1: SWAPPED operands -> D[n][row]
  f32x4 acc1[4][4] = {};
  int cur = 0;
  for (int t = 0; t < TE; ++t) {
    *(uint4*)&Ash[apos(aq, ar) * 8] = a;
    __syncthreads();
    if (t + 1 < TE) { issueW(g.W1e, t + 1, cur ^ 1); loadA(t + 1, a); }
    bf16x8 wfr[4], efr[4];
#pragma unroll
    for (int f = 0; f < 4; f++) {
      wfr[f] = *(const bf16x8*)&Bsh[cur][bpos(lhi, wave * 64 + f * 16 + l16) * 8];
      efr[f] = *(const bf16x8*)&Ash[apos(lhi, f * 16 + l16) * 8];
    }
#pragma unroll
    for (int fr = 0; fr < 4; fr++)
#pragma unroll
      for (int fc = 0; fc < 4; fc++)
        acc1[fr][fc] = __builtin_amdgcn_mfma_f32_16x16x32_bf16(wfr[fr], efr[fc], acc1[fr][fc], 0, 0, 0);
    __syncthreads();
    cur ^= 1;
  }

  issueW(g.W2s, 0, 0);

  // ---- epilogue-1: h = silu(acc1 + psum); Hsh in-place; global h (PERMUTED); wp partials
  float pw[4] = {0.f, 0.f, 0.f, 0.f};
#pragma unroll
  for (int fr = 0; fr < 4; fr++) {
    const int nb = wave * 64 + fr * 16 + lhi * 4;
    const int kc = nb >> 3, off = nb & 7;
    uint2 wr = *(const uint2*)(g.w384 + nb);
    const __hip_bfloat16* w4 = (const __hip_bfloat16*)&wr;
#pragma unroll
    for (int fc = 0; fc < 4; fc++) {
      const int row = fc * 16 + l16;
      unsigned short* slot = &Hsh[(kc * 64 + (row ^ swz(kc & 3))) * 8 + off];
      uint2 pr = *(const uint2*)slot;
      const __hip_bfloat16* pp = (const __hip_bfloat16*)&pr;
      alignas(8) __hip_bfloat16 hb[4];
#pragma unroll
      for (int r = 0; r < 4; r++) {
        const float hv = siluf(acc1[fr][fc][r] + __bfloat162float(pp[r]));
        hb[r] = __float2bfloat16(hv);
        pw[fc] += hv * __bfloat162float(w4[r]);
      }
      *(uint2*)slot = *(const uint2*)hb;
      *(uint2*)(g.h_out + (size_t)Rk[row] * HIDc + nb) = *(const uint2*)hb;
    }
  }

  // ---- wp reduce
#pragma unroll
  for (int fc = 0; fc < 4; fc++) {
    pw[fc] += __shfl_xor(pw[fc], 16);
    pw[fc] += __shfl_xor(pw[fc], 32);
  }
  if (lane < 16) {
#pragma unroll
    for (int fc = 0; fc < 4; fc++) wps[wave][fc * 16 + lane] = pw[fc];
  }
  __syncthreads();   // h in Hsh visible; wps visible; W2s(0) landed
  if (tid < 64) {
    const float s = wps[0][tid] + wps[1][tid] + wps[2][tid] + wps[3][tid];
    const float wpt = tanhf(s + g.b2L[384]);
    const int rk = Rk[tid];
#pragma unroll
    for (int c = 0; c < 3; c++)
      g.mp[(size_t)rk * 3 + c] = wpt * RnL[tid][c];
  }

  // ---- phase 2: out2 = h @ W2s. Barrier-free; Bsh[2] dbuf, counted vmcnt(4).
  f32x4 acc2[4][4] = {};
  cur = 0;
  for (int t = 0; t < T2; ++t) {
    if (t + 1 < T2) { issueW(g.W2s, t + 1, cur ^ 1); wait_vm4(); }
    else            { wait_vm0(); }
    bf16x8 afr[4], bfr[4];
#pragma unroll
    for (int f = 0; f < 4; f++) {
      const int kc = t * 4 + lhi;
      afr[f] = *(const bf16x8*)&Hsh[(kc * 64 + ((f * 16 + l16) ^ swz(lhi))) * 8];
      bfr[f] = *(const bf16x8*)&Bsh[cur][bpos(lhi, wave * 64 + f * 16 + l16) * 8];
    }
#pragma unroll
    for (int fr = 0; fr < 4; fr++)
#pragma unroll
      for (int fc = 0; fc < 4; fc++)
        acc2[fr][fc] = __builtin_amdgcn_mfma_f32_16x16x32_bf16(afr[fr], bfr[fc], acc2[fr][fc], 0, 0, 0);
    cur ^= 1;
  }

  // ---- epilogue-2: wv (PERMUTED) | e_new (edge order)
#pragma unroll
  for (int fr = 0; fr < 4; fr++) {
#pragma unroll
    for (int fc = 0; fc < 4; fc++) {
      const int n = wave * 64 + fc * 16 + l16;
#pragma unroll
      for (int r = 0; r < 4; r++) {
        const int lr = fr * 16 + lhi * 4 + r;
        const int row = row0 + lr;
        const float valf = acc2[fr][fc][r];
        if (n < 128) {
          g.wv_out[(size_t)Rk[lr] * 128 + n] = __float2bfloat16(valf + g.b2L[256 + n]);
        } else {
          const float sv = siluf(valf + g.b2L[257 + n]);
          g.e_bf_out[(size_t)row * ED + (n - 128)] = __float2bfloat16(sv);
          if (g.write_e_f32) g.e_f32_out[(size_t)row * ED + (n - 128)] = sv;
        }
      }
    }
  }
}

// ---- LayerNorm (layer 0 only). 4 nodes/block, wave per node.
__global__ __launch_bounds__(256) void ln_k(const float* __restrict__ s,
                                            const float* __restrict__ gl, const float* __restrict__ bl,
                                            __hip_bfloat16* __restrict__ s_ln) {
  const int wave = threadIdx.x >> 6, lane = threadIdx.x & 63;
  const int node = blockIdx.x * 4 + wave;
  const float* srow = s + (size_t)node * SD;
  float x[4], sum = 0.f, sq = 0.f;
#pragma unroll
  for (int i = 0; i < 4; i++) { x[i] = srow[lane * 4 + i]; sum += x[i]; sq += x[i] * x[i]; }
#pragma unroll
  for (int off = 1; off < 64; off <<= 1) { sum += __shfl_xor(sum, off); sq += __shfl_xor(sq, off); }
  const float mu = sum * (1.0f / SD);
  const float var = sq * (1.0f / SD) - mu * mu;
  const float rstd = rsqrtf(var + 1e-5f);
#pragma unroll
  for (int i = 0; i < 4; i++) {
    const int c = lane * 4 + i;
    s_ln[(size_t)node * SD + c] = __float2bfloat16(gl[c] * (x[i] - mu) * rstd + bl[c]);
  }
}

__global__ void cvt_e_k(const float* __restrict__ e, __hip_bfloat16* __restrict__ ebf) {
  const int i = blockIdx.x * blockDim.x + threadIdx.x;
  const float* p = e + (size_t)i * 8;
  alignas(16) __hip_bfloat16 t8[8];
#pragma unroll
  for (int j = 0; j < 8; j++) t8[j] = __float2bfloat16(p[j]);
  *(uint4*)(ebf + (size_t)i * 8) = *(const uint4*)t8;
}

__global__ void count_k(const int* __restrict__ tgt, int* __restrict__ rawcnt) {
  const int e = blockIdx.x * blockDim.x + threadIdx.x;
  if (e < NE) atomicAdd(&rawcnt[tgt[e]], 1);
}

__global__ __launch_bounds__(256) void scan_k(const int* __restrict__ rawcnt, int* __restrict__ off) {
  __shared__ int ts[256];
  const int tid = threadIdx.x;
  const int base = tid * 32;
  int local[32];
  int s = 0;
#pragma unroll
  for (int i = 0; i < 32; i++) { local[i] = s; s += rawcnt[base + i]; }
  ts[tid] = s;
  __syncthreads();
  if (tid == 0) {
    int acc = 0;
    for (int i = 0; i < 256; i++) { int t = ts[i]; ts[i] = acc; acc += t; }
    off[NN] = acc;
  }
  __syncthreads();
  const int pre = ts[tid];
#pragma unroll
  for (int i = 0; i < 32; i++) off[base + i] = pre + local[i];
}

__global__ void scatter_k(const int* __restrict__ tgt, const int* __restrict__ srcp,
                          const int* __restrict__ off,
                          int* __restrict__ cursor, int* __restrict__ rank, int* __restrict__ psrc) {
  const int e = blockIdx.x * blockDim.x + threadIdx.x;
  if (e < NE) {
    const int t = tgt[e];
    const int pos = off[t] + atomicAdd(&cursor[t], 1);
    rank[e] = pos;
    psrc[pos] = srcp[e];
  }
}

// ---- CSR aggregation: one block per node; sequential payload reads.
__global__ __launch_bounds__(256) void agg_k(const int* __restrict__ off, const int* __restrict__ psrc,
                                             const __hip_bfloat16* __restrict__ h,
                                             const __hip_bfloat16* __restrict__ wv,
                                             const float* __restrict__ mp,
                                             const float* __restrict__ rnp,
                                             const float* __restrict__ v_old,
                                             float* __restrict__ v_new,
                                             float* __restrict__ Hagg,
                                             float* __restrict__ p_o,
                                             int hasv) {
  const int n = blockIdx.x;
  const int c = threadIdx.x;
  const int e0 = off[n], e1 = off[n + 1];
  const int c3 = c >> 6, ln = c & 63;
  float hs = 0.f, vs = 0.f, ps = 0.f;
  int j = e0;
  for (; j + 2 <= e1; j += 2) {
    const float h0 = __bfloat162float(h[(size_t)j * HIDc + c]);
    const float h1 = __bfloat162float(h[(size_t)(j + 1) * HIDc + c]);
    hs += h0 + h1;
    if (c < 192) {
      const int s0 = psrc[j], s1 = psrc[j + 1];
      float m0 = __bfloat162float(wv[(size_t)j * 128 + 64 + ln]) * rnp[j * 3 + c3];
      float m1 = __bfloat162float(wv[(size_t)(j + 1) * 128 + 64 + ln]) * rnp[(j + 1) * 3 + c3];
      if (hasv) {
        m0 += __bfloat162float(wv[(size_t)j * 128 + ln]) * v_old[(size_t)s0 * 192 + c];
        m1 += __bfloat162float(wv[(size_t)(j + 1) * 128 + ln]) * v_old[(size_t)s1 * 192 + c];
      }
      vs += m0 + m1;
    } else if (c < 195) {
      ps += mp[j * 3 + (c - 192)] + mp[(j + 1) * 3 + (c - 192)];
    }
  }
  for (; j < e1; j++) {
    hs += __bfloat162float(h[(size_t)j * HIDc + c]);
    if (c < 192) {
      float mv = __bfloat162float(wv[(size_t)j * 128 + 64 + ln]) * rnp[j * 3 + c3];
      if (hasv) mv += __bfloat162float(wv[(size_t)j * 128 + ln]) * v_old[(size_t)psrc[j] * 192 + c];
      vs += mv;
    } else if (c < 195) {
      ps += mp[j * 3 + (c - 192)];
    }
  }
  Hagg[(size_t)n * HIDc + c] = hs;
  const float inv = 1.0f / fmaxf((float)(e1 - e0), 1.0f);
  if (c < 192)      v_new[(size_t)n * 192 + c] = v_old[(size_t)n * 192 + c] + vs * inv;
  else if (c < 195) p_o[n * 3 + (c - 192)]    += ps * inv;
}

__global__ void zero_k(float* __restrict__ ptr, int n) {
  const int i = blockIdx.x * blockDim.x + threadIdx.x;
  if (i < n) ptr[i] = 0.f;
}

// ---- weight prep -> swizzled streams
__global__ void prep_w1abs_k(const float* __restrict__ W1, __hip_bfloat16* __restrict__ W1aS,
                             __hip_bfloat16* __restrict__ W1bS) {
  const int idx = blockIdx.x * blockDim.x + threadIdx.x;
  if (idx >= NL * T2 * 1024) return;
  const int p = idx & 1023, t = (idx >> 10) % T2, l = idx / (T2 * 1024);
  const int kc = p >> 8, n = (p & 255) ^ swz(kc);
  alignas(16) __hip_bfloat16 a8[8], b8[8];
#pragma unroll
  for (int j = 0; j < 8; j++) {
    const int k = t * 32 + kc * 8 + j;
    a8[j] = __float2bfloat16(W1[((size_t)l * DINc + k) * HIDc + n]);
    b8[j] = __float2bfloat16(W1[((size_t)l * DINc + 256 + k) * HIDc + n]);
  }
  *(uint4*)(W1aS + (size_t)idx * 8) = *(const uint4*)a8;
  *(uint4*)(W1bS + (size_t)idx * 8) = *(const uint4*)b8;
}

__global__ void prep_w1es_k(const float* __restrict__ W1, __hip_bfloat16* __restrict__ W1eS) {
  const int idx = blockIdx.x * blockDim.x + threadIdx.x;
  if (idx >= NL * TE * 1024) return;
  const int p = idx & 1023, t = (idx >> 10) % TE, l = idx / (TE * 1024);
  const int kc = p >> 8, n = (p & 255) ^ swz(kc);
  alignas(16) __hip_bfloat16 e8[8];
#pragma unroll
  for (int j = 0; j < 8; j++) {
    const int k = t * 32 + kc * 8 + j;
    const int row = (k < 128) ? (512 + k) : ((k < 132) ? (640 + (k - 128)) : -1);
    e8[j] = __float2bfloat16(row >= 0 ? W1[((size_t)l * DINc + row) * HIDc + n] : 0.f);
  }
  *(uint4*)(W1eS + (size_t)idx * 8) = *(const uint4*)e8;
}

__global__ void prep_w2s_k(const float* __restrict__ W2, __hip_bfloat16* __restrict__ W2sS,
                           __hip_bfloat16* __restrict__ W2aS) {
  const int idx = blockIdx.x * blockDim.x + threadIdx.x;
  if (idx >= NL * T2 * 1024) return;
  const int p = idx & 1023, t = (idx >> 10) & 7, l = idx >> 13;
  const int kc = p >> 8, n = (p & 255) ^ swz(kc);
  const float* W2l = W2 + (size_t)l * HIDc * DOUTc;
  const int cs = (n < 128) ? (256 + n) : (257 + n);
  alignas(16) __hip_bfloat16 s8[8], a8[8];
#pragma unroll
  for (int j = 0; j < 8; j++) {
    const int k = t * 32 + kc * 8 + j;
    s8[j] = __float2bfloat16(W2l[(size_t)k * DOUTc + cs]);
    a8[j] = __float2bfloat16(W2l[(size_t)k * DOUTc + n]);
  }
  *(uint4*)(W2sS + (size_t)idx * 8) = *(const uint4*)s8;
  *(uint4*)(W2aS + (size_t)idx * 8) = *(const uint4*)a8;
}

__global__ void prep_uts_k(const float* __restrict__ U1, const float* __restrict__ U2,
                           __hip_bfloat16* __restrict__ U1S, __hip_bfloat16* __restrict__ U2S) {
  const int idx = blockIdx.x * blockDim.x + threadIdx.x;
  if (idx >= NL * T2 * 1024) return;
  const int p = idx & 1023, t = (idx >> 10) & 7, l = idx >> 13;
  const int kc = p >> 8, n = (p & 255) ^ swz(kc);
  alignas(16) __hip_bfloat16 u1[8], u2[8];
#pragma unroll
  for (int j = 0; j < 8; j++) {
    const int k = t * 32 + kc * 8 + j;
    u1[j] = __float2bfloat16(U1[((size_t)l * HIDc + k) * HIDc + n]);
    u2[j] = __float2bfloat16(U2[((size_t)l * HIDc + k) * HIDc + n]);
  }
  *(uint4*)(U1S + (size_t)idx * 8) = *(const uint4*)u1;
  *(uint4*)(U2S + (size_t)idx * 8) = *(const uint4*)u2;
}

__global__ void prep_w384_k(const float* __restrict__ W2, __hip_bfloat16* __restrict__ w384) {
  const int idx = blockIdx.x * blockDim.x + threadIdx.x;
  if (idx >= NL * HIDc) return;
  const int k = idx & 255, l = idx >> 8;
  w384[idx] = __float2bfloat16(W2[((size_t)l * HIDc + k) * DOUTc + 384]);
}

}  // namespace

extern "C" void kernel_launch(void* const* d_in, const int* in_sizes, int n_in,
                              void* d_out, int out_size, void* d_ws, size_t ws_size,
                              hipStream_t stream) {
  (void)in_sizes; (void)n_in; (void)out_size; (void)ws_size;
  const float* s_in = (const float*)d_in[0];
  const float* v_in = (const float*)d_in[1];
  const float* p_in = (const float*)d_in[2];
  const float* e_in = (const float*)d_in[3];
  const int*   ei   = (const int*)d_in[4];
  const float* ln_g = (const float*)d_in[5];
  const float* ln_b = (const float*)d_in[6];
  const float* W1   = (const float*)d_in[7];
  const float* b1   = (const float*)d_in[8];
  const float* W2   = (const float*)d_in[9];
  const float* b2   = (const float*)d_in[10];
  const float* U1   = (const float*)d_in[11];
  const float* bU1  = (const float*)d_in[12];
  const float* U2   = (const float*)d_in[13];
  const float* bU2  = (const float*)d_in[14];

  float* s_o = (float*)d_out;
  float* v_o = s_o + (size_t)NN * SD;
  float* e_o = v_o + (size_t)NN * 192;
  float* p_o = e_o + (size_t)NE * ED;

  const int* srcp = ei;
  const int* tgtp = ei + NE;

  char* wp = (char*)d_ws;
  auto alloc = [&](size_t bytes) -> char* {
    char* r = wp; wp += (bytes + 255) & ~(size_t)255; return r;
  };
  __hip_bfloat16* s_ln = (__hip_bfloat16*)alloc((size_t)NN * SD * 2);
  __hip_bfloat16* hbuf = (__hip_bfloat16*)alloc((size_t)NE * HIDc * 2);
  __hip_bfloat16* ebf  = (__hip_bfloat16*)alloc((size_t)NE * ED * 2);
  __hip_bfloat16* wvbuf= (__hip_bfloat16*)alloc((size_t)NE * 128 * 2);
  __hip_bfloat16* p1buf= (__hip_bfloat16*)alloc((size_t)NN * SD * 2);
  __hip_bfloat16* p2buf= (__hip_bfloat16*)alloc((size_t)NN * SD * 2);
  float* rnpbuf= (float*)alloc((size_t)NE * 3 * 4);
  float* Hagg  = (float*)alloc((size_t)NN * SD * 4);
  float* vprev = (float*)alloc((size_t)NN * 192 * 4);
  float* mpbuf = (float*)alloc((size_t)NE * 3 * 4);
  float* zerobias = (float*)alloc(256 * 4);
  int*   rawcnt= (int*)alloc((size_t)NN * 4);
  int*   offb  = (int*)alloc((size_t)(NN + 1) * 4);
  int*   cursor= (int*)alloc((size_t)NN * 4);
  int*   rankb = (int*)alloc((size_t)NE * 4);
  int*   psrcb = (int*)alloc((size_t)NE * 4);
  __hip_bfloat16* W1aS = (__hip_bfloat16*)alloc((size_t)NL * T2 * 1024 * 8 * 2);
  __hip_bfloat16* W1bS = (__hip_bfloat16*)alloc((size_t)NL * T2 * 1024 * 8 * 2);
  __hip_bfloat16* W1eS = (__hip_bfloat16*)alloc((size_t)NL * TE * 1024 * 8 * 2);
  __hip_bfloat16* W2sS = (__hip_bfloat16*)alloc((size_t)NL * T2 * 1024 * 8 * 2);
  __hip_bfloat16* W2aS = (__hip_bfloat16*)alloc((size_t)NL * T2 * 1024 * 8 * 2);
  __hip_bfloat16* U1S  = (__hip_bfloat16*)alloc((size_t)NL * T2 * 1024 * 8 * 2);
  __hip_bfloat16* U2S  = (__hip_bfloat16*)alloc((size_t)NL * T2 * 1024 * 8 * 2);
  __hip_bfloat16* w384 = (__hip_bfloat16*)alloc((size_t)NL * HIDc * 2);

  hipMemcpyAsync(s_o, s_in, (size_t)NN * SD * 4, hipMemcpyDeviceToDevice, stream);
  hipMemcpyAsync(vprev, v_in, (size_t)NN * 192 * 4, hipMemcpyDeviceToDevice, stream);
  hipMemcpyAsync(p_o, p_in, (size_t)NN * 3 * 4, hipMemcpyDeviceToDevice, stream);

  prep_w1abs_k<<<(NL * T2 * 1024 + 255) / 256, 256, 0, stream>>>(W1, W1aS, W1bS);
  prep_w1es_k<<<(NL * TE * 1024 + 255) / 256, 256, 0, stream>>>(W1, W1eS);
  prep_w2s_k<<<(NL * T2 * 1024 + 255) / 256, 256, 0, stream>>>(W2, W2sS, W2aS);
  prep_uts_k<<<(NL * T2 * 1024 + 255) / 256, 256, 0, stream>>>(U1, U2, U1S, U2S);
  prep_w384_k<<<(NL * HIDc + 255) / 256, 256, 0, stream>>>(W2, w384);
  cvt_e_k<<<NE * ED / 8 / 256, 256, 0, stream>>>(e_in, ebf);
  zero_k<<<1, 256, 0, stream>>>(zerobias, 256);

  // ---- CSR build (once; edge_index layer-invariant)
  zero_k<<<(NN + 255) / 256, 256, 0, stream>>>((float*)rawcnt, NN);
  zero_k<<<(NN + 255) / 256, 256, 0, stream>>>((float*)cursor, NN);
  count_k<<<NE / 256, 256, 0, stream>>>(tgtp, rawcnt);
  scan_k<<<1, 256, 0, stream>>>(rawcnt, offb);
  scatter_k<<<NE / 256, 256, 0, stream>>>(tgtp, srcp, offb, cursor, rankb, psrcb);

  // ---- layer 0: LN + P1/P2 (subsequent layers fold these into node3)
  ln_k<<<NN / 4, 256, 0, stream>>>(s_o, ln_g, ln_b, s_ln);
  GemmArgs gp{};
  gp.Wt = W1aS; gp.bias = b1; gp.bf_out = p1buf;
  gp.Wtb = W1bS; gp.biasb = zerobias; gp.bf_outb = p2buf;
  gp.Abf = s_ln; gp.dual = 1;
  gemm_k<256, 64><<<2 * NN / 64, 256, 0, stream>>>(gp);

  for (int l = 0; l < NL; l++) {
    // fused edge kernel: attrs + h + out2 (h/wv/mp/rnp written at rank[e])
    FusedArgs gf{};
    gf.W1e = W1eS + (size_t)l * TE * 1024 * 8;
    gf.W2s = W2sS + (size_t)l * T2 * 1024 * 8;
    gf.b2L = b2 + l * DOUTc;
    gf.src = srcp; gf.tgt = tgtp; gf.rank = rankb;
    gf.pos = p_o; gf.e_bf = ebf;
    gf.p1 = p1buf; gf.p2 = p2buf; gf.w384 = w384 + l * HIDc;
    gf.rnp = rnpbuf; gf.mp = mpbuf;
    gf.h_out = hbuf; gf.wv_out = wvbuf; gf.e_bf_out = ebf; gf.e_f32_out = e_o;
    gf.write_e_f32 = (l == NL - 1) ? 1 : 0;
    fused_k<<<NE / 64, 256, 0, stream>>>(gf);

    // v ping-pong: 5 layers -> final write lands in v_o.
    const float* vold = (l & 1) ? (const float*)v_o : (const float*)vprev;
    float* vnew = (l & 1) ? vprev : v_o;
    agg_k<<<NN, 256, 0, stream>>>(offb, psrcb, hbuf, wvbuf, mpbuf, rnpbuf,
                                  vold, vnew, Hagg, p_o, (l > 0) ? 1 : 0);

    // fused node MLP (+ next-layer LN/P1/P2 when l<4)
    Node3Args gn{};
    gn.W2a = W2aS + (size_t)l * T2 * 1024 * 8;
    gn.U1s = U1S + (size_t)l * T2 * 1024 * 8;
    gn.U2s = U2S + (size_t)l * T2 * 1024 * 8;
    gn.b2L = b2 + l * DOUTc; gn.bU1 = bU1 + l * HIDc; gn.bU2 = bU2 + l * HIDc;
    gn.Hagg = Hagg; gn.rawcnt = rawcnt; gn.s_out = s_o;
    if (l < NL - 1) {
      gn.W1an = W1aS + (size_t)(l + 1) * T2 * 1024 * 8;
      gn.W1bn = W1bS + (size_t)(l + 1) * T2 * 1024 * 8;
      gn.b1n = b1 + (l + 1) * HIDc;
      gn.lng = ln_g + (l + 1) * SD; gn.lnb = ln_b + (l + 1) * SD;
      gn.p1 = p1buf; gn.p2 = p2buf;
      node3_k<0><<<NN / 32, 256, 0, stream>>>(gn);
    } else {
      node3_k<1><<<NN / 32, 256, 0, stream>>>(gn);
    }
  }
}

// Round 16
// 1001.259 us; speedup vs baseline: 1.4025x; 1.0172x over previous
//
#include <hip/hip_runtime.h>
#include <hip/hip_bf16.h>

namespace {

constexpr int NN   = 8192;    // nodes
constexpr int NE   = 131072;  // edges
constexpr int SD   = 256;     // SDIM
constexpr int ED   = 128;     // EDIM
constexpr int NL   = 5;       // layers
constexpr int DINc = 644;     // 2*SD + ED + 4
constexpr int KE   = 160;     // edge-GEMM K: 128 e + 4 scalars + pad
constexpr int TE   = 5;       // KE/32
constexpr int T2   = 8;       // 256/32
constexpr int DOUTc= 513;
constexpr int HIDc = 256;

typedef __bf16 bf16x8 __attribute__((ext_vector_type(8)));
typedef float  f32x4  __attribute__((ext_vector_type(4)));

__device__ __forceinline__ float siluf(float x) { return x / (1.0f + __expf(-x)); }

// async global->LDS, 16B/lane. LDS dest is wave-uniform base (+lane*16 in HW).
__device__ __forceinline__ void gl_lds16(const void* gsrc, void* lds_uniform_base) {
  __builtin_amdgcn_global_load_lds(
      (const __attribute__((address_space(1))) unsigned int*)gsrc,
      (__attribute__((address_space(3))) unsigned int*)lds_uniform_base, 16, 0, 0);
}

__device__ __forceinline__ void wait_vm4() {
  asm volatile("s_waitcnt vmcnt(4)" ::: "memory");
  __builtin_amdgcn_sched_barrier(0);
}
__device__ __forceinline__ void wait_vm0() {
  asm volatile("s_waitcnt vmcnt(0)" ::: "memory");
  __builtin_amdgcn_sched_barrier(0);
}

// bank-group swizzle: (5x)&7 is a permutation on 0..7.
__device__ __host__ __forceinline__ int swz(int kc) { return (kc * 5) & 7; }
__device__ __forceinline__ int apos(int kc, int row) { return kc * 64  + (row ^ swz(kc)); }
__device__ __forceinline__ int bpos(int kc, int n)   { return kc * 256 + (n   ^ swz(kc)); }

enum { SRC_BF16 = 1 };

struct GemmArgs {
  const __hip_bfloat16* Wt;     // swizzled B stream
  const float* bias;
  const __hip_bfloat16* Abf;
  __hip_bfloat16* bf_out;
  const __hip_bfloat16* Wtb;    // dual second half
  const float* biasb;
  __hip_bfloat16* bf_outb;
  int dual;
};

__device__ __forceinline__ uint4 cvt8f(const float* p) {
  alignas(16) __hip_bfloat16 t8[8];
#pragma unroll
  for (int i = 0; i < 8; i++) t8[i] = __float2bfloat16(p[i]);
  return *(const uint4*)t8;
}

// Layer-0 P1/P2: BM=64, BN=256, dual-launch. A-panel staged once; barrier-free loop.
template<int KTOT, int BM>
__global__ __launch_bounds__(256) void gemm_k(GemmArgs g) {
  constexpr int T = KTOT / 32;
  constexpr int NC = KTOT / 8;
  constexpr int RPT = 256 / BM;
  constexpr int RMASK = RPT - 1;
  __shared__ alignas(16) unsigned short Apan[NC * BM * 8];
  __shared__ alignas(16) unsigned short Bsh[2][4 * 256 * 8];
  const int tid = threadIdx.x, lane = tid & 63, wave = tid >> 6;
  const int l16 = lane & 15, lhi = lane >> 4;
  const __hip_bfloat16* wtp = g.Wt;
  const float* biasp = g.bias;
  __hip_bfloat16* outp = g.bf_out;
  int blk = blockIdx.x;
  {
    const int half = gridDim.x >> 1;
    if (g.dual && blk >= half) { blk -= half; wtp = g.Wtb; biasp = g.biasb; outp = g.bf_outb; }
  }
  const int row0 = blk * BM;
  const int ar = tid / RPT, aq = tid % RPT;
  const int arow = row0 + ar;
  f32x4 acc[BM / 16][4] = {};

  auto issueB = [&](int t, int buf) {
    const __hip_bfloat16* src = wtp + (size_t)t * 1024 * 8;
    unsigned short* dst = &Bsh[buf][0];
#pragma unroll
    for (int i = 0; i < 4; i++)
      gl_lds16(src + (size_t)(i * 256 + wave * 64 + lane) * 8, dst + (i * 256 + wave * 64) * 8);
  };

  issueB(0, 0);
#pragma unroll
  for (int j = 0; j < NC / RPT; j++) {
    const int c = j * RPT + aq;
    uint4 o = *(const uint4*)(g.Abf + (size_t)arow * KTOT + c * 8);
    *(uint4*)&Apan[(c * BM + (ar ^ swz(aq))) * 8] = o;
  }
  __syncthreads();

  int cur = 0;
  for (int t = 0; t < T; ++t) {
    if (t + 1 < T) { issueB(t + 1, cur ^ 1); wait_vm4(); }
    else           { wait_vm0(); }
    bf16x8 bfr[4];
#pragma unroll
    for (int f = 0; f < 4; f++)
      bfr[f] = *(const bf16x8*)&Bsh[cur][bpos(lhi, wave * 64 + f * 16 + l16) * 8];
#pragma unroll
    for (int fr = 0; fr < BM / 16; fr++) {
      const int kc = t * 4 + lhi;
      const bf16x8 afr = *(const bf16x8*)&Apan[(kc * BM + ((fr * 16 + l16) ^ swz(kc & RMASK))) * 8];
#pragma unroll
      for (int fc = 0; fc < 4; fc++)
        acc[fr][fc] = __builtin_amdgcn_mfma_f32_16x16x32_bf16(afr, bfr[fc], acc[fr][fc], 0, 0, 0);
    }
    cur ^= 1;
  }

#pragma unroll
  for (int fr = 0; fr < BM / 16; fr++) {
#pragma unroll
    for (int fc = 0; fc < 4; fc++) {
      const int n = wave * 64 + fc * 16 + l16;
#pragma unroll
      for (int r = 0; r < 4; r++) {
        const int row = row0 + fr * 16 + lhi * 4 + r;
        outp[(size_t)row * HIDc + n] = __float2bfloat16(acc[fr][fc][r] + biasp[n]);
      }
    }
  }
}

// ==== fused node kernel: s-update + node MLP + next-layer LN + P1/P2 ====
struct Node3Args {
  const __hip_bfloat16* W2a;
  const __hip_bfloat16* U1s;
  const __hip_bfloat16* U2s;
  const __hip_bfloat16* W1an;   // next layer streams
  const __hip_bfloat16* W1bn;
  const float* b2L;
  const float* bU1;
  const float* bU2;
  const float* b1n;             // next layer b1
  const float* lng;             // next layer ln params
  const float* lnb;
  const float* Hagg;
  const int* rawcnt;
  float* s_out;
  __hip_bfloat16* p1;
  __hip_bfloat16* p2;
};

template<int LAST>
__global__ __launch_bounds__(256) void node3_k(Node3Args g) {
  constexpr int BM = 32, RPT = 8, NC = 32, T = 8;
  __shared__ alignas(16) unsigned short Apan[NC * BM * 8];      // 16 KB
  __shared__ alignas(16) unsigned short Bsh[2][4 * 256 * 8];    // 32 KB
  __shared__ float red[2][4][32];
  const int tid = threadIdx.x, lane = tid & 63, wave = tid >> 6;
  const int l16 = lane & 15, lhi = lane >> 4;
  const int row0 = blockIdx.x * BM;
  const int ar = tid >> 3, aq = tid & 7;

  auto issueB = [&](const __hip_bfloat16* W, int t, int buf) {
    const __hip_bfloat16* src = W + (size_t)t * 1024 * 8;
    unsigned short* dst = &Bsh[buf][0];
#pragma unroll
    for (int i = 0; i < 4; i++)
      gl_lds16(src + (size_t)(i * 256 + wave * 64 + lane) * 8, dst + (i * 256 + wave * 64) * 8);
  };

  f32x4 acc[4][2];   // SWAPPED: acc[n-blk][row-blk], D[n][row]
  auto kloop = [&](const __hip_bfloat16* W) {
#pragma unroll
    for (int i = 0; i < 4; i++)
#pragma unroll
      for (int j = 0; j < 2; j++) acc[i][j] = f32x4{0.f, 0.f, 0.f, 0.f};
    int cur = 0;
    for (int t = 0; t < T; ++t) {
      if (t + 1 < T) { issueB(W, t + 1, cur ^ 1); wait_vm4(); }
      else           { wait_vm0(); }
      bf16x8 wfr[4], afr[2];
#pragma unroll
      for (int f = 0; f < 4; f++)
        wfr[f] = *(const bf16x8*)&Bsh[cur][bpos(lhi, wave * 64 + f * 16 + l16) * 8];
#pragma unroll
      for (int f = 0; f < 2; f++) {
        const int kc = t * 4 + lhi;
        afr[f] = *(const bf16x8*)&Apan[(kc * BM + ((f * 16 + l16) ^ swz(kc & 7))) * 8];
      }
#pragma unroll
      for (int fr = 0; fr < 4; fr++)
#pragma unroll
        for (int fc = 0; fc < 2; fc++)
          acc[fr][fc] = __builtin_amdgcn_mfma_f32_16x16x32_bf16(wfr[fr], afr[fc], acc[fr][fc], 0, 0, 0);
      cur ^= 1;
    }
  };

  // ---- stage Hagg panel (f32 -> bf16)
  issueB(g.W2a, 0, 0);
#pragma unroll
  for (int j = 0; j < NC / RPT; j++) {
    const int c = j * RPT + aq;
    uint4 o = cvt8f(g.Hagg + (size_t)(row0 + ar) * SD + c * 8);
    *(uint4*)&Apan[(c * BM + (ar ^ swz(aq))) * 8] = o;
  }
  __syncthreads();

  // ---- step A: Hagg @ W2a -> s1
  kloop(g.W2a);
  __syncthreads();
  if constexpr (!LAST) issueB(g.U1s, 0, 0);

#pragma unroll
  for (int fr = 0; fr < 4; fr++) {
    const int nb = wave * 64 + fr * 16 + lhi * 4;
    const int kc = nb >> 3, off = nb & 7;
    const f32x4 b4 = *(const f32x4*)(g.b2L + nb);
#pragma unroll
    for (int fc = 0; fc < 2; fc++) {
      const int row = fc * 16 + l16;
      const float rc = (float)g.rawcnt[row0 + row];
      float* sp = g.s_out + (size_t)(row0 + row) * SD + nb;
      f32x4 sold = *(const f32x4*)sp;
      alignas(8) __hip_bfloat16 hb[4];
      f32x4 s1;
#pragma unroll
      for (int r = 0; r < 4; r++) {
        s1[r] = sold[r] + acc[fr][fc][r] + rc * b4[r];
        hb[r] = __float2bfloat16(s1[r]);
      }
      *(f32x4*)sp = s1;
      if constexpr (!LAST)
        *(uint2*)&Apan[(kc * BM + (row ^ swz(kc & 7))) * 8 + off] = *(const uint2*)hb;
    }
  }
  if constexpr (LAST) return;

  __syncthreads();   // s1 panel visible; U1(0) landed

  // ---- step B: t = silu(s1@U1 + bU1) -> Apan
  kloop(g.U1s);
  __syncthreads();
  issueB(g.U2s, 0, 0);
#pragma unroll
  for (int fr = 0; fr < 4; fr++) {
    const int nb = wave * 64 + fr * 16 + lhi * 4;
    const int kc = nb >> 3, off = nb & 7;
    const f32x4 b4 = *(const f32x4*)(g.bU1 + nb);
#pragma unroll
    for (int fc = 0; fc < 2; fc++) {
      const int row = fc * 16 + l16;
      alignas(8) __hip_bfloat16 hb[4];
#pragma unroll
      for (int r = 0; r < 4; r++)
        hb[r] = __float2bfloat16(siluf(acc[fr][fc][r] + b4[r]));
      *(uint2*)&Apan[(kc * BM + (row ^ swz(kc & 7))) * 8 + off] = *(const uint2*)hb;
    }
  }
  __syncthreads();   // t panel visible; U2(0) landed

  // ---- step C: s2 = s1 + t@U2 + bU2 (s_o RMW); row stats for LN
  kloop(g.U2s);
  float psum[2] = {0.f, 0.f}, psq[2] = {0.f, 0.f};
#pragma unroll
  for (int fr = 0; fr < 4; fr++) {
    const int nb = wave * 64 + fr * 16 + lhi * 4;
    const f32x4 b4 = *(const f32x4*)(g.bU2 + nb);
#pragma unroll
    for (int fc = 0; fc < 2; fc++) {
      const int row = fc * 16 + l16;
      float* sp = g.s_out + (size_t)(row0 + row) * SD + nb;
      f32x4 sv = *(const f32x4*)sp;
#pragma unroll
      for (int r = 0; r < 4; r++) {
        sv[r] += acc[fr][fc][r] + b4[r];
        psum[fc] += sv[r];
        psq[fc] += sv[r] * sv[r];
      }
      *(f32x4*)sp = sv;
      acc[fr][fc] = sv;   // keep s2 in regs
    }
  }
#pragma unroll
  for (int fc = 0; fc < 2; fc++) {
    psum[fc] += __shfl_xor(psum[fc], 16); psum[fc] += __shfl_xor(psum[fc], 32);
    psq[fc]  += __shfl_xor(psq[fc], 16);  psq[fc]  += __shfl_xor(psq[fc], 32);
  }
  if (lane < 16) {
    red[0][wave][lane] = psum[0]; red[0][wave][16 + lane] = psum[1];
    red[1][wave][lane] = psq[0];  red[1][wave][16 + lane] = psq[1];
  }
  __syncthreads();   // red visible; all waves done reading Apan (t-panel)

  float mu2[2], rs2[2];
#pragma unroll
  for (int fc = 0; fc < 2; fc++) {
    const int ri = fc * 16 + l16;
    const float S = red[0][0][ri] + red[0][1][ri] + red[0][2][ri] + red[0][3][ri];
    const float Q = red[1][0][ri] + red[1][1][ri] + red[1][2][ri] + red[1][3][ri];
    const float mu = S * (1.0f / SD);
    const float var = Q * (1.0f / SD) - mu * mu;
    mu2[fc] = mu; rs2[fc] = rsqrtf(var + 1e-5f);
  }
  // ---- s_ln = LN_{l+1}(s2) -> Apan
#pragma unroll
  for (int fr = 0; fr < 4; fr++) {
    const int nb = wave * 64 + fr * 16 + lhi * 4;
    const int kc = nb >> 3, off = nb & 7;
    const f32x4 g4 = *(const f32x4*)(g.lng + nb);
    const f32x4 bb4 = *(const f32x4*)(g.lnb + nb);
#pragma unroll
    for (int fc = 0; fc < 2; fc++) {
      const int row = fc * 16 + l16;
      alignas(8) __hip_bfloat16 hb[4];
#pragma unroll
      for (int r = 0; r < 4; r++)
        hb[r] = __float2bfloat16(g4[r] * (acc[fr][fc][r] - mu2[fc]) * rs2[fc] + bb4[r]);
      *(uint2*)&Apan[(kc * BM + (row ^ swz(kc & 7))) * 8 + off] = *(const uint2*)hb;
    }
  }
  issueB(g.W1an, 0, 0);
  __syncthreads();   // s_ln panel visible; W1a(0) landed

  // ---- step D: P1 = s_ln @ W1a_{l+1} + b1_{l+1}
  kloop(g.W1an);
#pragma unroll
  for (int fr = 0; fr < 4; fr++) {
    const int nb = wave * 64 + fr * 16 + lhi * 4;
    const f32x4 b4 = *(const f32x4*)(g.b1n + nb);
#pragma unroll
    for (int fc = 0; fc < 2; fc++) {
      const int row = fc * 16 + l16;
      alignas(8) __hip_bfloat16 hb[4];
#pragma unroll
      for (int r = 0; r < 4; r++)
        hb[r] = __float2bfloat16(acc[fr][fc][r] + b4[r]);
      *(uint2*)(g.p1 + (size_t)(row0 + row) * SD + nb) = *(const uint2*)hb;
    }
  }
  // ---- step E: P2 = s_ln @ W1b_{l+1}
  issueB(g.W1bn, 0, 0);
  kloop(g.W1bn);
#pragma unroll
  for (int fr = 0; fr < 4; fr++) {
    const int nb = wave * 64 + fr * 16 + lhi * 4;
#pragma unroll
    for (int fc = 0; fc < 2; fc++) {
      const int row = fc * 16 + l16;
      alignas(8) __hip_bfloat16 hb[4];
#pragma unroll
      for (int r = 0; r < 4; r++)
        hb[r] = __float2bfloat16(acc[fr][fc][r]);
      *(uint2*)(g.p2 + (size_t)(row0 + row) * SD + nb) = *(const uint2*)hb;
    }
  }
}

// ==== fused edge kernel (R13 structure, CSR-ORDERED edges) ====
// Block handles ranks [row0, row0+64). All edge payloads stream at rank order;
// tgt-side gathers (P2, pos[tgt]) are tile-local (CSR ⇒ few distinct tgt/tile).
struct FusedArgs {
  const __hip_bfloat16* W1e;
  const __hip_bfloat16* W2s;
  const float* b2L;
  const int* psrc;              // [NE] src node at rank
  const int* ptgt;              // [NE] tgt node at rank
  const int* iperm;             // [NE] original edge id at rank
  const float* pos;             // p_o [NN][3]
  const __hip_bfloat16* e_bf;   // [NE][128], RANK order
  const __hip_bfloat16* p1;
  const __hip_bfloat16* p2;
  const __hip_bfloat16* w384;
  float* rnp;                   // [NE][3] out, rank order
  float* mp;                    // [NE][3] out, rank order
  __hip_bfloat16* h_out;        // [NE][256], rank order
  __hip_bfloat16* wv_out;       // [NE][128], rank order
  __hip_bfloat16* e_bf_out;     // [NE][128], rank order
  float* e_f32_out;             // d_out e region, EDGE order (scatter via iperm)
  int write_e_f32;
};

__global__ __launch_bounds__(256) void fused_k(FusedArgs g) {
  __shared__ alignas(16) unsigned short Ash[4 * 64 * 8];        // 4 KB (edge A)
  __shared__ alignas(16) unsigned short Bsh[2][4 * 256 * 8];    // 32 KB (W stream dbuf)
  __shared__ alignas(16) unsigned short Hsh[32 * 64 * 8];       // 32 KB (psum -> h)
  __shared__ float wps[4][64];
  __shared__ float RnL[64][3];
  __shared__ unsigned int EdL[64][2];
  __shared__ int Ei[64];
  const int tid = threadIdx.x, lane = tid & 63, wave = tid >> 6;
  const int l16 = lane & 15, lhi = lane >> 4;
  const int row0 = blockIdx.x * 64;
  const int ar = tid >> 2, aq = tid & 3;
  const int arow = row0 + ar;
  const int sn = g.psrc[arow], tn = g.ptgt[arow];

  auto issueW = [&](const __hip_bfloat16* W, int t, int buf) {
    const __hip_bfloat16* src = W + (size_t)t * 1024 * 8;
    unsigned short* dst = &Bsh[buf][0];
#pragma unroll
    for (int i = 0; i < 4; i++)
      gl_lds16(src + (size_t)(i * 256 + wave * 64 + lane) * 8, dst + (i * 256 + wave * 64) * 8);
  };
  auto loadA = [&](int t, uint4& o) {
    if (t < 4) {
      o = *(const uint4*)(g.e_bf + (size_t)arow * ED + t * 32 + aq * 8);
    } else {
      o.x = o.y = o.z = o.w = 0;
      if (aq == 0) { o.x = EdL[ar][0]; o.y = EdL[ar][1]; }
    }
  };

  uint4 a;
  loadA(0, a);
  issueW(g.W1e, 0, 0);

  // ---- in-kernel edge attrs (tgt-side reads tile-local): d,a,pn -> EdL; rn -> RnL + rnp
  if (tid < 64) {
    const int e = row0 + tid;   // rank
    Ei[tid] = g.iperm[e];
    const int s_ = g.psrc[e], t_ = g.ptgt[e];
    const float sx = g.pos[s_ * 3], sy = g.pos[s_ * 3 + 1], sz = g.pos[s_ * 3 + 2];
    const float tx = g.pos[t_ * 3], ty = g.pos[t_ * 3 + 1], tz = g.pos[t_ * 3 + 2];
    const float rx = tx - sx, ry = ty - sy, rz = tz - sz;
    const float av = tx * sx + ty * sy + tz * sz;
    const float rr = rx * rx + ry * ry + rz * rz;
    const float d = sqrtf(fmaxf(rr, 1e-6f));
    const float inv = 1.0f / (1.0f + d);
    const float r0 = rx * inv, r1 = ry * inv, r2 = rz * inv;
    RnL[tid][0] = r0; RnL[tid][1] = r1; RnL[tid][2] = r2;
    g.rnp[e * 3] = r0; g.rnp[e * 3 + 1] = r1; g.rnp[e * 3 + 2] = r2;
    alignas(8) __hip_bfloat16 q[4];
    q[0] = __float2bfloat16(d);
    q[1] = __float2bfloat16(av);
    q[2] = __float2bfloat16(sqrtf(sx * sx + sy * sy + sz * sz));
    q[3] = __float2bfloat16(sqrtf(tx * tx + ty * ty + tz * tz));
    EdL[tid][0] = ((const unsigned*)q)[0];
    EdL[tid][1] = ((const unsigned*)q)[1];
  }

  // ---- stage Psum = P1[sn] + P2[tn] into Hsh (P2 rows tile-local -> L1/L2 hits)
#pragma unroll
  for (int j = 0; j < 8; j++) {
    const int c = j * 4 + aq;
    uint4 r1 = *(const uint4*)(g.p1 + (size_t)sn * SD + c * 8);
    uint4 r2 = *(const uint4*)(g.p2 + (size_t)tn * SD + c * 8);
    const __hip_bfloat16* h1 = (const __hip_bfloat16*)&r1;
    const __hip_bfloat16* h2 = (const __hip_bfloat16*)&r2;
    alignas(16) __hip_bfloat16 o8[8];
#pragma unroll
    for (int m = 0; m < 8; m++)
      o8[m] = __float2bfloat16(__bfloat162float(h1[m]) + __bfloat162float(h2[m]));
    *(uint4*)&Hsh[(c * 64 + (ar ^ swz(aq))) * 8] = *(const uint4*)o8;
  }

  // ---- phase 1: SWAPPED operands -> D[n][row]
  f32x4 acc1[4][4] = {};
  int cur = 0;
  for (int t = 0; t < TE; ++t) {
    *(uint4*)&Ash[apos(aq, ar) * 8] = a;
    __syncthreads();
    if (t + 1 < TE) { issueW(g.W1e, t + 1, cur ^ 1); loadA(t + 1, a); }
    bf16x8 wfr[4], efr[4];
#pragma unroll
    for (int f = 0; f < 4; f++) {
      wfr[f] = *(const bf16x8*)&Bsh[cur][bpos(lhi, wave * 64 + f * 16 + l16) * 8];
      efr[f] = *(const bf16x8*)&Ash[apos(lhi, f * 16 + l16) * 8];
    }
#pragma unroll
    for (int fr = 0; fr < 4; fr++)
#pragma unroll
      for (int fc = 0; fc < 4; fc++)
        acc1[fr][fc] = __builtin_amdgcn_mfma_f32_16x16x32_bf16(wfr[fr], efr[fc], acc1[fr][fc], 0, 0, 0);
    __syncthreads();
    cur ^= 1;
  }

  issueW(g.W2s, 0, 0);

  // ---- epilogue-1: h = silu(acc1 + psum); Hsh in-place; global h (streaming); wp partials
  float pw[4] = {0.f, 0.f, 0.f, 0.f};
#pragma unroll
  for (int fr = 0; fr < 4; fr++) {
    const int nb = wave * 64 + fr * 16 + lhi * 4;
    const int kc = nb >> 3, off = nb & 7;
    uint2 wr = *(const uint2*)(g.w384 + nb);
    const __hip_bfloat16* w4 = (const __hip_bfloat16*)&wr;
#pragma unroll
    for (int fc = 0; fc < 4; fc++) {
      const int row = fc * 16 + l16;
      unsigned short* slot = &Hsh[(kc * 64 + (row ^ swz(kc & 3))) * 8 + off];
      uint2 pr = *(const uint2*)slot;
      const __hip_bfloat16* pp = (const __hip_bfloat16*)&pr;
      alignas(8) __hip_bfloat16 hb[4];
#pragma unroll
      for (int r = 0; r < 4; r++) {
        const float hv = siluf(acc1[fr][fc][r] + __bfloat162float(pp[r]));
        hb[r] = __float2bfloat16(hv);
        pw[fc] += hv * __bfloat162float(w4[r]);
      }
      *(uint2*)slot = *(const uint2*)hb;
      *(uint2*)(g.h_out + (size_t)(row0 + row) * HIDc + nb) = *(const uint2*)hb;
    }
  }

  // ---- wp reduce
#pragma unroll
  for (int fc = 0; fc < 4; fc++) {
    pw[fc] += __shfl_xor(pw[fc], 16);
    pw[fc] += __shfl_xor(pw[fc], 32);
  }
  if (lane < 16) {
#pragma unroll
    for (int fc = 0; fc < 4; fc++) wps[wave][fc * 16 + lane] = pw[fc];
  }
  __syncthreads();   // h in Hsh visible; wps visible; W2s(0) landed
  if (tid < 64) {
    const float s = wps[0][tid] + wps[1][tid] + wps[2][tid] + wps[3][tid];
    const float wpt = tanhf(s + g.b2L[384]);
    const int e = row0 + tid;
#pragma unroll
    for (int c = 0; c < 3; c++)
      g.mp[(size_t)e * 3 + c] = wpt * RnL[tid][c];
  }

  // ---- phase 2: out2 = h @ W2s. Barrier-free; Bsh[2] dbuf, counted vmcnt(4).
  f32x4 acc2[4][4] = {};
  cur = 0;
  for (int t = 0; t < T2; ++t) {
    if (t + 1 < T2) { issueW(g.W2s, t + 1, cur ^ 1); wait_vm4(); }
    else            { wait_vm0(); }
    bf16x8 afr[4], bfr[4];
#pragma unroll
    for (int f = 0; f < 4; f++) {
      const int kc = t * 4 + lhi;
      afr[f] = *(const bf16x8*)&Hsh[(kc * 64 + ((f * 16 + l16) ^ swz(lhi))) * 8];
      bfr[f] = *(const bf16x8*)&Bsh[cur][bpos(lhi, wave * 64 + f * 16 + l16) * 8];
    }
#pragma unroll
    for (int fr = 0; fr < 4; fr++)
#pragma unroll
      for (int fc = 0; fc < 4; fc++)
        acc2[fr][fc] = __builtin_amdgcn_mfma_f32_16x16x32_bf16(afr[fr], bfr[fc], acc2[fr][fc], 0, 0, 0);
    cur ^= 1;
  }

  // ---- epilogue-2: wv | e_new (rank order); final-layer e f32 scattered via iperm
#pragma unroll
  for (int fr = 0; fr < 4; fr++) {
#pragma unroll
    for (int fc = 0; fc < 4; fc++) {
      const int n = wave * 64 + fc * 16 + l16;
#pragma unroll
      for (int r = 0; r < 4; r++) {
        const int lr = fr * 16 + lhi * 4 + r;
        const int row = row0 + lr;
        const float valf = acc2[fr][fc][r];
        if (n < 128) {
          g.wv_out[(size_t)row * 128 + n] = __float2bfloat16(valf + g.b2L[256 + n]);
        } else {
          const float sv = siluf(valf + g.b2L[257 + n]);
          g.e_bf_out[(size_t)row * ED + (n - 128)] = __float2bfloat16(sv);
          if (g.write_e_f32) g.e_f32_out[(size_t)Ei[lr] * ED + (n - 128)] = sv;
        }
      }
    }
  }
}

// ---- LayerNorm (layer 0 only). 4 nodes/block, wave per node.
__global__ __launch_bounds__(256) void ln_k(const float* __restrict__ s,
                                            const float* __restrict__ gl, const float* __restrict__ bl,
                                            __hip_bfloat16* __restrict__ s_ln) {
  const int wave = threadIdx.x >> 6, lane = threadIdx.x & 63;
  const int node = blockIdx.x * 4 + wave;
  const float* srow = s + (size_t)node * SD;
  float x[4], sum = 0.f, sq = 0.f;
#pragma unroll
  for (int i = 0; i < 4; i++) { x[i] = srow[lane * 4 + i]; sum += x[i]; sq += x[i] * x[i]; }
#pragma unroll
  for (int off = 1; off < 64; off <<= 1) { sum += __shfl_xor(sum, off); sq += __shfl_xor(sq, off); }
  const float mu = sum * (1.0f / SD);
  const float var = sq * (1.0f / SD) - mu * mu;
  const float rstd = rsqrtf(var + 1e-5f);
#pragma unroll
  for (int i = 0; i < 4; i++) {
    const int c = lane * 4 + i;
    s_ln[(size_t)node * SD + c] = __float2bfloat16(gl[c] * (x[i] - mu) * rstd + bl[c]);
  }
}

// ---- e conversion into RANK order: thread handles (rank, chunk)
__global__ void cvt_e_k(const float* __restrict__ e, const int* __restrict__ iperm,
                        __hip_bfloat16* __restrict__ ebf) {
  const int idx = blockIdx.x * blockDim.x + threadIdx.x;   // NE*16 threads
  const int pos = idx >> 4, c = idx & 15;
  const int src_e = iperm[pos];
  const float* p = e + (size_t)src_e * ED + c * 8;
  alignas(16) __hip_bfloat16 t8[8];
#pragma unroll
  for (int j = 0; j < 8; j++) t8[j] = __float2bfloat16(p[j]);
  *(uint4*)(ebf + (size_t)pos * ED + c * 8) = *(const uint4*)t8;
}

__global__ void count_k(const int* __restrict__ tgt, int* __restrict__ rawcnt) {
  const int e = blockIdx.x * blockDim.x + threadIdx.x;
  if (e < NE) atomicAdd(&rawcnt[tgt[e]], 1);
}

__global__ __launch_bounds__(256) void scan_k(const int* __restrict__ rawcnt, int* __restrict__ off) {
  __shared__ int ts[256];
  const int tid = threadIdx.x;
  const int base = tid * 32;
  int local[32];
  int s = 0;
#pragma unroll
  for (int i = 0; i < 32; i++) { local[i] = s; s += rawcnt[base + i]; }
  ts[tid] = s;
  __syncthreads();
  if (tid == 0) {
    int acc = 0;
    for (int i = 0; i < 256; i++) { int t = ts[i]; ts[i] = acc; acc += t; }
    off[NN] = acc;
  }
  __syncthreads();
  const int pre = ts[tid];
#pragma unroll
  for (int i = 0; i < 32; i++) off[base + i] = pre + local[i];
}

// ---- scatter: psrc/ptgt/iperm at CSR position
__global__ void scatter_k(const int* __restrict__ tgt, const int* __restrict__ srcp,
                          const int* __restrict__ off, int* __restrict__ cursor,
                          int* __restrict__ psrc, int* __restrict__ ptgt, int* __restrict__ iperm) {
  const int e = blockIdx.x * blockDim.x + threadIdx.x;
  if (e < NE) {
    const int t = tgt[e];
    const int pos = off[t] + atomicAdd(&cursor[t], 1);
    psrc[pos] = srcp[e];
    ptgt[pos] = t;
    iperm[pos] = e;
  }
}

// ---- CSR aggregation: one block per node; sequential payload reads.
__global__ __launch_bounds__(256) void agg_k(const int* __restrict__ off, const int* __restrict__ psrc,
                                             const __hip_bfloat16* __restrict__ h,
                                             const __hip_bfloat16* __restrict__ wv,
                                             const float* __restrict__ mp,
                                             const float* __restrict__ rnp,
                                             const float* __restrict__ v_old,
                                             float* __restrict__ v_new,
                                             float* __restrict__ Hagg,
                                             float* __restrict__ p_o,
                                             int hasv) {
  const int n = blockIdx.x;
  const int c = threadIdx.x;
  const int e0 = off[n], e1 = off[n + 1];
  const int c3 = c >> 6, ln = c & 63;
  float hs = 0.f, vs = 0.f, ps = 0.f;
  int j = e0;
  for (; j + 2 <= e1; j += 2) {
    const float h0 = __bfloat162float(h[(size_t)j * HIDc + c]);
    const float h1 = __bfloat162float(h[(size_t)(j + 1) * HIDc + c]);
    hs += h0 + h1;
    if (c < 192) {
      const int s0 = psrc[j], s1 = psrc[j + 1];
      float m0 = __bfloat162float(wv[(size_t)j * 128 + 64 + ln]) * rnp[j * 3 + c3];
      float m1 = __bfloat162float(wv[(size_t)(j + 1) * 128 + 64 + ln]) * rnp[(j + 1) * 3 + c3];
      if (hasv) {
        m0 += __bfloat162float(wv[(size_t)j * 128 + ln]) * v_old[(size_t)s0 * 192 + c];
        m1 += __bfloat162float(wv[(size_t)(j + 1) * 128 + ln]) * v_old[(size_t)s1 * 192 + c];
      }
      vs += m0 + m1;
    } else if (c < 195) {
      ps += mp[j * 3 + (c - 192)] + mp[(j + 1) * 3 + (c - 192)];
    }
  }
  for (; j < e1; j++) {
    hs += __bfloat162float(h[(size_t)j * HIDc + c]);
    if (c < 192) {
      float mv = __bfloat162float(wv[(size_t)j * 128 + 64 + ln]) * rnp[j * 3 + c3];
      if (hasv) mv += __bfloat162float(wv[(size_t)j * 128 + ln]) * v_old[(size_t)psrc[j] * 192 + c];
      vs += mv;
    } else if (c < 195) {
      ps += mp[j * 3 + (c - 192)];
    }
  }
  Hagg[(size_t)n * HIDc + c] = hs;
  const float inv = 1.0f / fmaxf((float)(e1 - e0), 1.0f);
  if (c < 192)      v_new[(size_t)n * 192 + c] = v_old[(size_t)n * 192 + c] + vs * inv;
  else if (c < 195) p_o[n * 3 + (c - 192)]    += ps * inv;
}

__global__ void zero_k(float* __restrict__ ptr, int n) {
  const int i = blockIdx.x * blockDim.x + threadIdx.x;
  if (i < n) ptr[i] = 0.f;
}

// ---- weight prep -> swizzled streams
__global__ void prep_w1abs_k(const float* __restrict__ W1, __hip_bfloat16* __restrict__ W1aS,
                             __hip_bfloat16* __restrict__ W1bS) {
  const int idx = blockIdx.x * blockDim.x + threadIdx.x;
  if (idx >= NL * T2 * 1024) return;
  const int p = idx & 1023, t = (idx >> 10) % T2, l = idx / (T2 * 1024);
  const int kc = p >> 8, n = (p & 255) ^ swz(kc);
  alignas(16) __hip_bfloat16 a8[8], b8[8];
#pragma unroll
  for (int j = 0; j < 8; j++) {
    const int k = t * 32 + kc * 8 + j;
    a8[j] = __float2bfloat16(W1[((size_t)l * DINc + k) * HIDc + n]);
    b8[j] = __float2bfloat16(W1[((size_t)l * DINc + 256 + k) * HIDc + n]);
  }
  *(uint4*)(W1aS + (size_t)idx * 8) = *(const uint4*)a8;
  *(uint4*)(W1bS + (size_t)idx * 8) = *(const uint4*)b8;
}

__global__ void prep_w1es_k(const float* __restrict__ W1, __hip_bfloat16* __restrict__ W1eS) {
  const int idx = blockIdx.x * blockDim.x + threadIdx.x;
  if (idx >= NL * TE * 1024) return;
  const int p = idx & 1023, t = (idx >> 10) % TE, l = idx / (TE * 1024);
  const int kc = p >> 8, n = (p & 255) ^ swz(kc);
  alignas(16) __hip_bfloat16 e8[8];
#pragma unroll
  for (int j = 0; j < 8; j++) {
    const int k = t * 32 + kc * 8 + j;
    const int row = (k < 128) ? (512 + k) : ((k < 132) ? (640 + (k - 128)) : -1);
    e8[j] = __float2bfloat16(row >= 0 ? W1[((size_t)l * DINc + row) * HIDc + n] : 0.f);
  }
  *(uint4*)(W1eS + (size_t)idx * 8) = *(const uint4*)e8;
}

__global__ void prep_w2s_k(const float* __restrict__ W2, __hip_bfloat16* __restrict__ W2sS,
                           __hip_bfloat16* __restrict__ W2aS) {
  const int idx = blockIdx.x * blockDim.x + threadIdx.x;
  if (idx >= NL * T2 * 1024) return;
  const int p = idx & 1023, t = (idx >> 10) & 7, l = idx >> 13;
  const int kc = p >> 8, n = (p & 255) ^ swz(kc);
  const float* W2l = W2 + (size_t)l * HIDc * DOUTc;
  const int cs = (n < 128) ? (256 + n) : (257 + n);
  alignas(16) __hip_bfloat16 s8[8], a8[8];
#pragma unroll
  for (int j = 0; j < 8; j++) {
    const int k = t * 32 + kc * 8 + j;
    s8[j] = __float2bfloat16(W2l[(size_t)k * DOUTc + cs]);
    a8[j] = __float2bfloat16(W2l[(size_t)k * DOUTc + n]);
  }
  *(uint4*)(W2sS + (size_t)idx * 8) = *(const uint4*)s8;
  *(uint4*)(W2aS + (size_t)idx * 8) = *(const uint4*)a8;
}

__global__ void prep_uts_k(const float* __restrict__ U1, const float* __restrict__ U2,
                           __hip_bfloat16* __restrict__ U1S, __hip_bfloat16* __restrict__ U2S) {
  const int idx = blockIdx.x * blockDim.x + threadIdx.x;
  if (idx >= NL * T2 * 1024) return;
  const int p = idx & 1023, t = (idx >> 10) & 7, l = idx >> 13;
  const int kc = p >> 8, n = (p & 255) ^ swz(kc);
  alignas(16) __hip_bfloat16 u1[8], u2[8];
#pragma unroll
  for (int j = 0; j < 8; j++) {
    const int k = t * 32 + kc * 8 + j;
    u1[j] = __float2bfloat16(U1[((size_t)l * HIDc + k) * HIDc + n]);
    u2[j] = __float2bfloat16(U2[((size_t)l * HIDc + k) * HIDc + n]);
  }
  *(uint4*)(U1S + (size_t)idx * 8) = *(const uint4*)u1;
  *(uint4*)(U2S + (size_t)idx * 8) = *(const uint4*)u2;
}

__global__ void prep_w384_k(const float* __restrict__ W2, __hip_bfloat16* __restrict__ w384) {
  const int idx = blockIdx.x * blockDim.x + threadIdx.x;
  if (idx >= NL * HIDc) return;
  const int k = idx & 255, l = idx >> 8;
  w384[idx] = __float2bfloat16(W2[((size_t)l * HIDc + k) * DOUTc + 384]);
}

}  // namespace

extern "C" void kernel_launch(void* const* d_in, const int* in_sizes, int n_in,
                              void* d_out, int out_size, void* d_ws, size_t ws_size,
                              hipStream_t stream) {
  (void)in_sizes; (void)n_in; (void)out_size; (void)ws_size;
  const float* s_in = (const float*)d_in[0];
  const float* v_in = (const float*)d_in[1];
  const float* p_in = (const float*)d_in[2];
  const float* e_in = (const float*)d_in[3];
  const int*   ei   = (const int*)d_in[4];
  const float* ln_g = (const float*)d_in[5];
  const float* ln_b = (const float*)d_in[6];
  const float* W1   = (const float*)d_in[7];
  const float* b1   = (const float*)d_in[8];
  const float* W2   = (const float*)d_in[9];
  const float* b2   = (const float*)d_in[10];
  const float* U1   = (const float*)d_in[11];
  const float* bU1  = (const float*)d_in[12];
  const float* U2   = (const float*)d_in[13];
  const float* bU2  = (const float*)d_in[14];

  float* s_o = (float*)d_out;
  float* v_o = s_o + (size_t)NN * SD;
  float* e_o = v_o + (size_t)NN * 192;
  float* p_o = e_o + (size_t)NE * ED;

  const int* srcp = ei;
  const int* tgtp = ei + NE;

  char* wp = (char*)d_ws;
  auto alloc = [&](size_t bytes) -> char* {
    char* r = wp; wp += (bytes + 255) & ~(size_t)255; return r;
  };
  __hip_bfloat16* s_ln = (__hip_bfloat16*)alloc((size_t)NN * SD * 2);
  __hip_bfloat16* hbuf = (__hip_bfloat16*)alloc((size_t)NE * HIDc * 2);
  __hip_bfloat16* ebf  = (__hip_bfloat16*)alloc((size_t)NE * ED * 2);
  __hip_bfloat16* wvbuf= (__hip_bfloat16*)alloc((size_t)NE * 128 * 2);
  __hip_bfloat16* p1buf= (__hip_bfloat16*)alloc((size_t)NN * SD * 2);
  __hip_bfloat16* p2buf= (__hip_bfloat16*)alloc((size_t)NN * SD * 2);
  float* rnpbuf= (float*)alloc((size_t)NE * 3 * 4);
  float* Hagg  = (float*)alloc((size_t)NN * SD * 4);
  float* vprev = (float*)alloc((size_t)NN * 192 * 4);
  float* mpbuf = (float*)alloc((size_t)NE * 3 * 4);
  float* zerobias = (float*)alloc(256 * 4);
  int*   rawcnt= (int*)alloc((size_t)NN * 4);
  int*   offb  = (int*)alloc((size_t)(NN + 1) * 4);
  int*   cursor= (int*)alloc((size_t)NN * 4);
  int*   psrcb = (int*)alloc((size_t)NE * 4);
  int*   ptgtb = (int*)alloc((size_t)NE * 4);
  int*   ipermb= (int*)alloc((size_t)NE * 4);
  __hip_bfloat16* W1aS = (__hip_bfloat16*)alloc((size_t)NL * T2 * 1024 * 8 * 2);
  __hip_bfloat16* W1bS = (__hip_bfloat16*)alloc((size_t)NL * T2 * 1024 * 8 * 2);
  __hip_bfloat16* W1eS = (__hip_bfloat16*)alloc((size_t)NL * TE * 1024 * 8 * 2);
  __hip_bfloat16* W2sS = (__hip_bfloat16*)alloc((size_t)NL * T2 * 1024 * 8 * 2);
  __hip_bfloat16* W2aS = (__hip_bfloat16*)alloc((size_t)NL * T2 * 1024 * 8 * 2);
  __hip_bfloat16* U1S  = (__hip_bfloat16*)alloc((size_t)NL * T2 * 1024 * 8 * 2);
  __hip_bfloat16* U2S  = (__hip_bfloat16*)alloc((size_t)NL * T2 * 1024 * 8 * 2);
  __hip_bfloat16* w384 = (__hip_bfloat16*)alloc((size_t)NL * HIDc * 2);

  hipMemcpyAsync(s_o, s_in, (size_t)NN * SD * 4, hipMemcpyDeviceToDevice, stream);
  hipMemcpyAsync(vprev, v_in, (size_t)NN * 192 * 4, hipMemcpyDeviceToDevice, stream);
  hipMemcpyAsync(p_o, p_in, (size_t)NN * 3 * 4, hipMemcpyDeviceToDevice, stream);

  prep_w1abs_k<<<(NL * T2 * 1024 + 255) / 256, 256, 0, stream>>>(W1, W1aS, W1bS);
  prep_w1es_k<<<(NL * TE * 1024 + 255) / 256, 256, 0, stream>>>(W1, W1eS);
  prep_w2s_k<<<(NL * T2 * 1024 + 255) / 256, 256, 0, stream>>>(W2, W2sS, W2aS);
  prep_uts_k<<<(NL * T2 * 1024 + 255) / 256, 256, 0, stream>>>(U1, U2, U1S, U2S);
  prep_w384_k<<<(NL * HIDc + 255) / 256, 256, 0, stream>>>(W2, w384);
  zero_k<<<1, 256, 0, stream>>>(zerobias, 256);

  // ---- CSR build (once; edge_index layer-invariant), then permuted e conversion
  zero_k<<<(NN + 255) / 256, 256, 0, stream>>>((float*)rawcnt, NN);
  zero_k<<<(NN + 255) / 256, 256, 0, stream>>>((float*)cursor, NN);
  count_k<<<NE / 256, 256, 0, stream>>>(tgtp, rawcnt);
  scan_k<<<1, 256, 0, stream>>>(rawcnt, offb);
  scatter_k<<<NE / 256, 256, 0, stream>>>(tgtp, srcp, offb, cursor, psrcb, ptgtb, ipermb);
  cvt_e_k<<<NE * 16 / 256, 256, 0, stream>>>(e_in, ipermb, ebf);

  // ---- layer 0: LN + P1/P2 (subsequent layers fold these into node3)
  ln_k<<<NN / 4, 256, 0, stream>>>(s_o, ln_g, ln_b, s_ln);
  GemmArgs gp{};
  gp.Wt = W1aS; gp.bias = b1; gp.bf_out = p1buf;
  gp.Wtb = W1bS; gp.biasb = zerobias; gp.bf_outb = p2buf;
  gp.Abf = s_ln; gp.dual = 1;
  gemm_k<256, 64><<<2 * NN / 64, 256, 0, stream>>>(gp);

  for (int l = 0; l < NL; l++) {
    // fused edge kernel (CSR-ordered): attrs + h + out2, all payloads streaming
    FusedArgs gf{};
    gf.W1e = W1eS + (size_t)l * TE * 1024 * 8;
    gf.W2s = W2sS + (size_t)l * T2 * 1024 * 8;
    gf.b2L = b2 + l * DOUTc;
    gf.psrc = psrcb; gf.ptgt = ptgtb; gf.iperm = ipermb;
    gf.pos = p_o; gf.e_bf = ebf;
    gf.p1 = p1buf; gf.p2 = p2buf; gf.w384 = w384 + l * HIDc;
    gf.rnp = rnpbuf; gf.mp = mpbuf;
    gf.h_out = hbuf; gf.wv_out = wvbuf; gf.e_bf_out = ebf; gf.e_f32_out = e_o;
    gf.write_e_f32 = (l == NL - 1) ? 1 : 0;
    fused_k<<<NE / 64, 256, 0, stream>>>(gf);

    // v ping-pong: 5 layers -> final write lands in v_o.
    const float* vold = (l & 1) ? (const float*)v_o : (const float*)vprev;
    float* vnew = (l & 1) ? vprev : v_o;
    agg_k<<<NN, 256, 0, stream>>>(offb, psrcb, hbuf, wvbuf, mpbuf, rnpbuf,
                                  vold, vnew, Hagg, p_o, (l > 0) ? 1 : 0);

    // fused node MLP (+ next-layer LN/P1/P2 when l<4)
    Node3Args gn{};
    gn.W2a = W2aS + (size_t)l * T2 * 1024 * 8;
    gn.U1s = U1S + (size_t)l * T2 * 1024 * 8;
    gn.U2s = U2S + (size_t)l * T2 * 1024 * 8;
    gn.b2L = b2 + l * DOUTc; gn.bU1 = bU1 + l * HIDc; gn.bU2 = bU2 + l * HIDc;
    gn.Hagg = Hagg; gn.rawcnt = rawcnt; gn.s_out = s_o;
    if (l < NL - 1) {
      gn.W1an = W1aS + (size_t)(l + 1) * T2 * 1024 * 8;
      gn.W1bn = W1bS + (size_t)(l + 1) * T2 * 1024 * 8;
      gn.b1n = b1 + (l + 1) * HIDc;
      gn.lng = ln_g + (l + 1) * SD; gn.lnb = ln_b + (l + 1) * SD;
      gn.p1 = p1buf; gn.p2 = p2buf;
      node3_k<0><<<NN / 32, 256, 0, stream>>>(gn);
    } else {
      node3_k<1><<<NN / 32, 256, 0, stream>>>(gn);
    }
  }
}

// Round 17
// 994.629 us; speedup vs baseline: 1.4118x; 1.0067x over previous
//
#include <hip/hip_runtime.h>
#include <hip/hip_bf16.h>

namespace {

constexpr int NN   = 8192;    // nodes
constexpr int NE   = 131072;  // edges
constexpr int SD   = 256;     // SDIM
constexpr int ED   = 128;     // EDIM
constexpr int NL   = 5;       // layers
constexpr int DINc = 644;     // 2*SD + ED + 4
constexpr int KE   = 160;     // edge-GEMM K: 128 e + 4 scalars + pad
constexpr int TE   = 5;       // KE/32
constexpr int T2   = 8;       // 256/32
constexpr int DOUTc= 513;
constexpr int HIDc = 256;

typedef __bf16 bf16x8 __attribute__((ext_vector_type(8)));
typedef float  f32x4  __attribute__((ext_vector_type(4)));

__device__ __forceinline__ float siluf(float x) { return x / (1.0f + __expf(-x)); }

// async global->LDS, 16B/lane. LDS dest is wave-uniform base (+lane*16 in HW).
__device__ __forceinline__ void gl_lds16(const void* gsrc, void* lds_uniform_base) {
  __builtin_amdgcn_global_load_lds(
      (const __attribute__((address_space(1))) unsigned int*)gsrc,
      (__attribute__((address_space(3))) unsigned int*)lds_uniform_base, 16, 0, 0);
}

__device__ __forceinline__ void wait_vm4() {
  asm volatile("s_waitcnt vmcnt(4)" ::: "memory");
  __builtin_amdgcn_sched_barrier(0);
}
__device__ __forceinline__ void wait_vm0() {
  asm volatile("s_waitcnt vmcnt(0)" ::: "memory");
  __builtin_amdgcn_sched_barrier(0);
}

// bank-group swizzle: (5x)&7 is a permutation on 0..7.
__device__ __host__ __forceinline__ int swz(int kc) { return (kc * 5) & 7; }
__device__ __forceinline__ int apos(int kc, int row) { return kc * 64  + (row ^ swz(kc)); }
__device__ __forceinline__ int bpos(int kc, int n)   { return kc * 256 + (n   ^ swz(kc)); }

enum { SRC_BF16 = 1 };

struct GemmArgs {
  const __hip_bfloat16* Wt;     // swizzled B stream
  const float* bias;
  const __hip_bfloat16* Abf;
  __hip_bfloat16* bf_out;
  const __hip_bfloat16* Wtb;    // dual second half
  const float* biasb;
  __hip_bfloat16* bf_outb;
  int dual;
};

__device__ __forceinline__ uint4 cvt8f(const float* p) {
  alignas(16) __hip_bfloat16 t8[8];
#pragma unroll
  for (int i = 0; i < 8; i++) t8[i] = __float2bfloat16(p[i]);
  return *(const uint4*)t8;
}

// Layer-0 P1/P2: BM=64, BN=256, dual-launch. A-panel staged once; barrier-free loop.
template<int KTOT, int BM>
__global__ __launch_bounds__(256) void gemm_k(GemmArgs g) {
  constexpr int T = KTOT / 32;
  constexpr int NC = KTOT / 8;
  constexpr int RPT = 256 / BM;
  constexpr int RMASK = RPT - 1;
  __shared__ alignas(16) unsigned short Apan[NC * BM * 8];
  __shared__ alignas(16) unsigned short Bsh[2][4 * 256 * 8];
  const int tid = threadIdx.x, lane = tid & 63, wave = tid >> 6;
  const int l16 = lane & 15, lhi = lane >> 4;
  const __hip_bfloat16* wtp = g.Wt;
  const float* biasp = g.bias;
  __hip_bfloat16* outp = g.bf_out;
  int blk = blockIdx.x;
  {
    const int half = gridDim.x >> 1;
    if (g.dual && blk >= half) { blk -= half; wtp = g.Wtb; biasp = g.biasb; outp = g.bf_outb; }
  }
  const int row0 = blk * BM;
  const int ar = tid / RPT, aq = tid % RPT;
  const int arow = row0 + ar;
  f32x4 acc[BM / 16][4] = {};

  auto issueB = [&](int t, int buf) {
    const __hip_bfloat16* src = wtp + (size_t)t * 1024 * 8;
    unsigned short* dst = &Bsh[buf][0];
#pragma unroll
    for (int i = 0; i < 4; i++)
      gl_lds16(src + (size_t)(i * 256 + wave * 64 + lane) * 8, dst + (i * 256 + wave * 64) * 8);
  };

  issueB(0, 0);
#pragma unroll
  for (int j = 0; j < NC / RPT; j++) {
    const int c = j * RPT + aq;
    uint4 o = *(const uint4*)(g.Abf + (size_t)arow * KTOT + c * 8);
    *(uint4*)&Apan[(c * BM + (ar ^ swz(aq))) * 8] = o;
  }
  __syncthreads();

  int cur = 0;
  for (int t = 0; t < T; ++t) {
    if (t + 1 < T) { issueB(t + 1, cur ^ 1); wait_vm4(); }
    else           { wait_vm0(); }
    bf16x8 bfr[4];
#pragma unroll
    for (int f = 0; f < 4; f++)
      bfr[f] = *(const bf16x8*)&Bsh[cur][bpos(lhi, wave * 64 + f * 16 + l16) * 8];
#pragma unroll
    for (int fr = 0; fr < BM / 16; fr++) {
      const int kc = t * 4 + lhi;
      const bf16x8 afr = *(const bf16x8*)&Apan[(kc * BM + ((fr * 16 + l16) ^ swz(kc & RMASK))) * 8];
#pragma unroll
      for (int fc = 0; fc < 4; fc++)
        acc[fr][fc] = __builtin_amdgcn_mfma_f32_16x16x32_bf16(afr, bfr[fc], acc[fr][fc], 0, 0, 0);
    }
    cur ^= 1;
  }

#pragma unroll
  for (int fr = 0; fr < BM / 16; fr++) {
#pragma unroll
    for (int fc = 0; fc < 4; fc++) {
      const int n = wave * 64 + fc * 16 + l16;
#pragma unroll
      for (int r = 0; r < 4; r++) {
        const int row = row0 + fr * 16 + lhi * 4 + r;
        outp[(size_t)row * HIDc + n] = __float2bfloat16(acc[fr][fc][r] + biasp[n]);
      }
    }
  }
}

// ==== fused node kernel: s-update + node MLP + next-layer LN + P1/P2 ====
struct Node3Args {
  const __hip_bfloat16* W2a;
  const __hip_bfloat16* U1s;
  const __hip_bfloat16* U2s;
  const __hip_bfloat16* W1an;   // next layer streams
  const __hip_bfloat16* W1bn;
  const float* b2L;
  const float* bU1;
  const float* bU2;
  const float* b1n;             // next layer b1
  const float* lng;             // next layer ln params
  const float* lnb;
  const float* Hagg;
  const int* rawcnt;
  float* s_out;
  __hip_bfloat16* p1;
  __hip_bfloat16* p2;
};

template<int LAST>
__global__ __launch_bounds__(256) void node3_k(Node3Args g) {
  constexpr int BM = 32, RPT = 8, NC = 32, T = 8;
  __shared__ alignas(16) unsigned short Apan[NC * BM * 8];      // 16 KB
  __shared__ alignas(16) unsigned short Bsh[2][4 * 256 * 8];    // 32 KB
  __shared__ float red[2][4][32];
  const int tid = threadIdx.x, lane = tid & 63, wave = tid >> 6;
  const int l16 = lane & 15, lhi = lane >> 4;
  const int row0 = blockIdx.x * BM;
  const int ar = tid >> 3, aq = tid & 7;

  auto issueB = [&](const __hip_bfloat16* W, int t, int buf) {
    const __hip_bfloat16* src = W + (size_t)t * 1024 * 8;
    unsigned short* dst = &Bsh[buf][0];
#pragma unroll
    for (int i = 0; i < 4; i++)
      gl_lds16(src + (size_t)(i * 256 + wave * 64 + lane) * 8, dst + (i * 256 + wave * 64) * 8);
  };

  f32x4 acc[4][2];   // SWAPPED: acc[n-blk][row-blk], D[n][row]
  auto kloop = [&](const __hip_bfloat16* W) {
#pragma unroll
    for (int i = 0; i < 4; i++)
#pragma unroll
      for (int j = 0; j < 2; j++) acc[i][j] = f32x4{0.f, 0.f, 0.f, 0.f};
    int cur = 0;
    for (int t = 0; t < T; ++t) {
      if (t + 1 < T) { issueB(W, t + 1, cur ^ 1); wait_vm4(); }
      else           { wait_vm0(); }
      bf16x8 wfr[4], afr[2];
#pragma unroll
      for (int f = 0; f < 4; f++)
        wfr[f] = *(const bf16x8*)&Bsh[cur][bpos(lhi, wave * 64 + f * 16 + l16) * 8];
#pragma unroll
      for (int f = 0; f < 2; f++) {
        const int kc = t * 4 + lhi;
        afr[f] = *(const bf16x8*)&Apan[(kc * BM + ((f * 16 + l16) ^ swz(kc & 7))) * 8];
      }
#pragma unroll
      for (int fr = 0; fr < 4; fr++)
#pragma unroll
        for (int fc = 0; fc < 2; fc++)
          acc[fr][fc] = __builtin_amdgcn_mfma_f32_16x16x32_bf16(wfr[fr], afr[fc], acc[fr][fc], 0, 0, 0);
      cur ^= 1;
    }
  };

  // ---- stage Hagg panel (f32 -> bf16)
  issueB(g.W2a, 0, 0);
#pragma unroll
  for (int j = 0; j < NC / RPT; j++) {
    const int c = j * RPT + aq;
    uint4 o = cvt8f(g.Hagg + (size_t)(row0 + ar) * SD + c * 8);
    *(uint4*)&Apan[(c * BM + (ar ^ swz(aq))) * 8] = o;
  }
  __syncthreads();

  // ---- step A: Hagg @ W2a -> s1
  kloop(g.W2a);
  __syncthreads();
  if constexpr (!LAST) issueB(g.U1s, 0, 0);

#pragma unroll
  for (int fr = 0; fr < 4; fr++) {
    const int nb = wave * 64 + fr * 16 + lhi * 4;
    const int kc = nb >> 3, off = nb & 7;
    const f32x4 b4 = *(const f32x4*)(g.b2L + nb);
#pragma unroll
    for (int fc = 0; fc < 2; fc++) {
      const int row = fc * 16 + l16;
      const float rc = (float)g.rawcnt[row0 + row];
      float* sp = g.s_out + (size_t)(row0 + row) * SD + nb;
      f32x4 sold = *(const f32x4*)sp;
      alignas(8) __hip_bfloat16 hb[4];
      f32x4 s1;
#pragma unroll
      for (int r = 0; r < 4; r++) {
        s1[r] = sold[r] + acc[fr][fc][r] + rc * b4[r];
        hb[r] = __float2bfloat16(s1[r]);
      }
      *(f32x4*)sp = s1;
      if constexpr (!LAST)
        *(uint2*)&Apan[(kc * BM + (row ^ swz(kc & 7))) * 8 + off] = *(const uint2*)hb;
    }
  }
  if constexpr (LAST) return;

  __syncthreads();   // s1 panel visible; U1(0) landed

  // ---- step B: t = silu(s1@U1 + bU1) -> Apan
  kloop(g.U1s);
  __syncthreads();
  issueB(g.U2s, 0, 0);
#pragma unroll
  for (int fr = 0; fr < 4; fr++) {
    const int nb = wave * 64 + fr * 16 + lhi * 4;
    const int kc = nb >> 3, off = nb & 7;
    const f32x4 b4 = *(const f32x4*)(g.bU1 + nb);
#pragma unroll
    for (int fc = 0; fc < 2; fc++) {
      const int row = fc * 16 + l16;
      alignas(8) __hip_bfloat16 hb[4];
#pragma unroll
      for (int r = 0; r < 4; r++)
        hb[r] = __float2bfloat16(siluf(acc[fr][fc][r] + b4[r]));
      *(uint2*)&Apan[(kc * BM + (row ^ swz(kc & 7))) * 8 + off] = *(const uint2*)hb;
    }
  }
  __syncthreads();   // t panel visible; U2(0) landed

  // ---- step C: s2 = s1 + t@U2 + bU2 (s_o RMW); row stats for LN
  kloop(g.U2s);
  float psum[2] = {0.f, 0.f}, psq[2] = {0.f, 0.f};
#pragma unroll
  for (int fr = 0; fr < 4; fr++) {
    const int nb = wave * 64 + fr * 16 + lhi * 4;
    const f32x4 b4 = *(const f32x4*)(g.bU2 + nb);
#pragma unroll
    for (int fc = 0; fc < 2; fc++) {
      const int row = fc * 16 + l16;
      float* sp = g.s_out + (size_t)(row0 + row) * SD + nb;
      f32x4 sv = *(const f32x4*)sp;
#pragma unroll
      for (int r = 0; r < 4; r++) {
        sv[r] += acc[fr][fc][r] + b4[r];
        psum[fc] += sv[r];
        psq[fc] += sv[r] * sv[r];
      }
      *(f32x4*)sp = sv;
      acc[fr][fc] = sv;   // keep s2 in regs
    }
  }
#pragma unroll
  for (int fc = 0; fc < 2; fc++) {
    psum[fc] += __shfl_xor(psum[fc], 16); psum[fc] += __shfl_xor(psum[fc], 32);
    psq[fc]  += __shfl_xor(psq[fc], 16);  psq[fc]  += __shfl_xor(psq[fc], 32);
  }
  if (lane < 16) {
    red[0][wave][lane] = psum[0]; red[0][wave][16 + lane] = psum[1];
    red[1][wave][lane] = psq[0];  red[1][wave][16 + lane] = psq[1];
  }
  __syncthreads();   // red visible; all waves done reading Apan (t-panel)

  float mu2[2], rs2[2];
#pragma unroll
  for (int fc = 0; fc < 2; fc++) {
    const int ri = fc * 16 + l16;
    const float S = red[0][0][ri] + red[0][1][ri] + red[0][2][ri] + red[0][3][ri];
    const float Q = red[1][0][ri] + red[1][1][ri] + red[1][2][ri] + red[1][3][ri];
    const float mu = S * (1.0f / SD);
    const float var = Q * (1.0f / SD) - mu * mu;
    mu2[fc] = mu; rs2[fc] = rsqrtf(var + 1e-5f);
  }
  // ---- s_ln = LN_{l+1}(s2) -> Apan
#pragma unroll
  for (int fr = 0; fr < 4; fr++) {
    const int nb = wave * 64 + fr * 16 + lhi * 4;
    const int kc = nb >> 3, off = nb & 7;
    const f32x4 g4 = *(const f32x4*)(g.lng + nb);
    const f32x4 bb4 = *(const f32x4*)(g.lnb + nb);
#pragma unroll
    for (int fc = 0; fc < 2; fc++) {
      const int row = fc * 16 + l16;
      alignas(8) __hip_bfloat16 hb[4];
#pragma unroll
      for (int r = 0; r < 4; r++)
        hb[r] = __float2bfloat16(g4[r] * (acc[fr][fc][r] - mu2[fc]) * rs2[fc] + bb4[r]);
      *(uint2*)&Apan[(kc * BM + (row ^ swz(kc & 7))) * 8 + off] = *(const uint2*)hb;
    }
  }
  issueB(g.W1an, 0, 0);
  __syncthreads();   // s_ln panel visible; W1a(0) landed

  // ---- step D: P1 = s_ln @ W1a_{l+1} + b1_{l+1}
  kloop(g.W1an);
#pragma unroll
  for (int fr = 0; fr < 4; fr++) {
    const int nb = wave * 64 + fr * 16 + lhi * 4;
    const f32x4 b4 = *(const f32x4*)(g.b1n + nb);
#pragma unroll
    for (int fc = 0; fc < 2; fc++) {
      const int row = fc * 16 + l16;
      alignas(8) __hip_bfloat16 hb[4];
#pragma unroll
      for (int r = 0; r < 4; r++)
        hb[r] = __float2bfloat16(acc[fr][fc][r] + b4[r]);
      *(uint2*)(g.p1 + (size_t)(row0 + row) * SD + nb) = *(const uint2*)hb;
    }
  }
  // ---- step E: P2 = s_ln @ W1b_{l+1}
  issueB(g.W1bn, 0, 0);
  kloop(g.W1bn);
#pragma unroll
  for (int fr = 0; fr < 4; fr++) {
    const int nb = wave * 64 + fr * 16 + lhi * 4;
#pragma unroll
    for (int fc = 0; fc < 2; fc++) {
      const int row = fc * 16 + l16;
      alignas(8) __hip_bfloat16 hb[4];
#pragma unroll
      for (int r = 0; r < 4; r++)
        hb[r] = __float2bfloat16(acc[fr][fc][r]);
      *(uint2*)(g.p2 + (size_t)(row0 + row) * SD + nb) = *(const uint2*)hb;
    }
  }
}

// ==== fused edge kernel (R13 structure, CSR-ORDERED edges) ====
struct FusedArgs {
  const __hip_bfloat16* W1e;
  const __hip_bfloat16* W2s;
  const float* b2L;
  const int* psrc;              // [NE] src node at rank
  const int* ptgt;              // [NE] tgt node at rank
  const int* iperm;             // [NE] original edge id at rank
  const float* pos;             // p_o [NN][3]
  const __hip_bfloat16* e_bf;   // [NE][128], RANK order
  const __hip_bfloat16* p1;
  const __hip_bfloat16* p2;
  const __hip_bfloat16* w384;
  float* rnp;                   // [NE][3] out, rank order
  float* mp;                    // [NE][3] out, rank order
  __hip_bfloat16* h_out;        // [NE][256], rank order
  __hip_bfloat16* wv_out;       // [NE][128], rank order
  __hip_bfloat16* e_bf_out;     // [NE][128], rank order
  float* e_f32_out;             // d_out e region, EDGE order (scatter via iperm)
  int write_e_f32;
};

__global__ __launch_bounds__(256) void fused_k(FusedArgs g) {
  __shared__ alignas(16) unsigned short Ash[4 * 64 * 8];        // 4 KB (edge A)
  __shared__ alignas(16) unsigned short Bsh[2][4 * 256 * 8];    // 32 KB (W stream dbuf)
  __shared__ alignas(16) unsigned short Hsh[32 * 64 * 8];       // 32 KB (psum -> h)
  __shared__ float wps[4][64];
  __shared__ float RnL[64][3];
  __shared__ unsigned int EdL[64][2];
  __shared__ int Ei[64];
  const int tid = threadIdx.x, lane = tid & 63, wave = tid >> 6;
  const int l16 = lane & 15, lhi = lane >> 4;
  const int row0 = blockIdx.x * 64;
  const int ar = tid >> 2, aq = tid & 3;
  const int arow = row0 + ar;
  const int sn = g.psrc[arow], tn = g.ptgt[arow];

  auto issueW = [&](const __hip_bfloat16* W, int t, int buf) {
    const __hip_bfloat16* src = W + (size_t)t * 1024 * 8;
    unsigned short* dst = &Bsh[buf][0];
#pragma unroll
    for (int i = 0; i < 4; i++)
      gl_lds16(src + (size_t)(i * 256 + wave * 64 + lane) * 8, dst + (i * 256 + wave * 64) * 8);
  };
  auto loadA = [&](int t, uint4& o) {
    if (t < 4) {
      o = *(const uint4*)(g.e_bf + (size_t)arow * ED + t * 32 + aq * 8);
    } else {
      o.x = o.y = o.z = o.w = 0;
      if (aq == 0) { o.x = EdL[ar][0]; o.y = EdL[ar][1]; }
    }
  };

  uint4 a;
  loadA(0, a);
  issueW(g.W1e, 0, 0);

  // ---- in-kernel edge attrs (tgt-side reads tile-local): d,a,pn -> EdL; rn -> RnL + rnp
  if (tid < 64) {
    const int e = row0 + tid;   // rank
    Ei[tid] = g.iperm[e];
    const int s_ = g.psrc[e], t_ = g.ptgt[e];
    const float sx = g.pos[s_ * 3], sy = g.pos[s_ * 3 + 1], sz = g.pos[s_ * 3 + 2];
    const float tx = g.pos[t_ * 3], ty = g.pos[t_ * 3 + 1], tz = g.pos[t_ * 3 + 2];
    const float rx = tx - sx, ry = ty - sy, rz = tz - sz;
    const float av = tx * sx + ty * sy + tz * sz;
    const float rr = rx * rx + ry * ry + rz * rz;
    const float d = sqrtf(fmaxf(rr, 1e-6f));
    const float inv = 1.0f / (1.0f + d);
    const float r0 = rx * inv, r1 = ry * inv, r2 = rz * inv;
    RnL[tid][0] = r0; RnL[tid][1] = r1; RnL[tid][2] = r2;
    g.rnp[e * 3] = r0; g.rnp[e * 3 + 1] = r1; g.rnp[e * 3 + 2] = r2;
    alignas(8) __hip_bfloat16 q[4];
    q[0] = __float2bfloat16(d);
    q[1] = __float2bfloat16(av);
    q[2] = __float2bfloat16(sqrtf(sx * sx + sy * sy + sz * sz));
    q[3] = __float2bfloat16(sqrtf(tx * tx + ty * ty + tz * tz));
    EdL[tid][0] = ((const unsigned*)q)[0];
    EdL[tid][1] = ((const unsigned*)q)[1];
  }

  // ---- stage Psum = P1[sn] + P2[tn] into Hsh (P2 rows tile-local -> L1/L2 hits)
#pragma unroll
  for (int j = 0; j < 8; j++) {
    const int c = j * 4 + aq;
    uint4 r1 = *(const uint4*)(g.p1 + (size_t)sn * SD + c * 8);
    uint4 r2 = *(const uint4*)(g.p2 + (size_t)tn * SD + c * 8);
    const __hip_bfloat16* h1 = (const __hip_bfloat16*)&r1;
    const __hip_bfloat16* h2 = (const __hip_bfloat16*)&r2;
    alignas(16) __hip_bfloat16 o8[8];
#pragma unroll
    for (int m = 0; m < 8; m++)
      o8[m] = __float2bfloat16(__bfloat162float(h1[m]) + __bfloat162float(h2[m]));
    *(uint4*)&Hsh[(c * 64 + (ar ^ swz(aq))) * 8] = *(const uint4*)o8;
  }

  // ---- phase 1: SWAPPED operands -> D[n][row]
  f32x4 acc1[4][4] = {};
  int cur = 0;
  for (int t = 0; t < TE; ++t) {
    *(uint4*)&Ash[apos(aq, ar) * 8] = a;
    __syncthreads();
    if (t + 1 < TE) { issueW(g.W1e, t + 1, cur ^ 1); loadA(t + 1, a); }
    bf16x8 wfr[4], efr[4];
#pragma unroll
    for (int f = 0; f < 4; f++) {
      wfr[f] = *(const bf16x8*)&Bsh[cur][bpos(lhi, wave * 64 + f * 16 + l16) * 8];
      efr[f] = *(const bf16x8*)&Ash[apos(lhi, f * 16 + l16) * 8];
    }
#pragma unroll
    for (int fr = 0; fr < 4; fr++)
#pragma unroll
      for (int fc = 0; fc < 4; fc++)
        acc1[fr][fc] = __builtin_amdgcn_mfma_f32_16x16x32_bf16(wfr[fr], efr[fc], acc1[fr][fc], 0, 0, 0);
    __syncthreads();
    cur ^= 1;
  }

  issueW(g.W2s, 0, 0);

  // ---- epilogue-1: h = silu(acc1 + psum); Hsh in-place; global h (streaming); wp partials
  float pw[4] = {0.f, 0.f, 0.f, 0.f};
#pragma unroll
  for (int fr = 0; fr < 4; fr++) {
    const int nb = wave * 64 + fr * 16 + lhi * 4;
    const int kc = nb >> 3, off = nb & 7;
    uint2 wr = *(const uint2*)(g.w384 + nb);
    const __hip_bfloat16* w4 = (const __hip_bfloat16*)&wr;
#pragma unroll
    for (int fc = 0; fc < 4; fc++) {
      const int row = fc * 16 + l16;
      unsigned short* slot = &Hsh[(kc * 64 + (row ^ swz(kc & 3))) * 8 + off];
      uint2 pr = *(const uint2*)slot;
      const __hip_bfloat16* pp = (const __hip_bfloat16*)&pr;
      alignas(8) __hip_bfloat16 hb[4];
#pragma unroll
      for (int r = 0; r < 4; r++) {
        const float hv = siluf(acc1[fr][fc][r] + __bfloat162float(pp[r]));
        hb[r] = __float2bfloat16(hv);
        pw[fc] += hv * __bfloat162float(w4[r]);
      }
      *(uint2*)slot = *(const uint2*)hb;
      *(uint2*)(g.h_out + (size_t)(row0 + row) * HIDc + nb) = *(const uint2*)hb;
    }
  }

  // ---- wp reduce
#pragma unroll
  for (int fc = 0; fc < 4; fc++) {
    pw[fc] += __shfl_xor(pw[fc], 16);
    pw[fc] += __shfl_xor(pw[fc], 32);
  }
  if (lane < 16) {
#pragma unroll
    for (int fc = 0; fc < 4; fc++) wps[wave][fc * 16 + lane] = pw[fc];
  }
  __syncthreads();   // h in Hsh visible; wps visible; W2s(0) landed
  if (tid < 64) {
    const float s = wps[0][tid] + wps[1][tid] + wps[2][tid] + wps[3][tid];
    const float wpt = tanhf(s + g.b2L[384]);
    const int e = row0 + tid;
#pragma unroll
    for (int c = 0; c < 3; c++)
      g.mp[(size_t)e * 3 + c] = wpt * RnL[tid][c];
  }

  // ---- phase 2: out2 = h @ W2s. Barrier-free; Bsh[2] dbuf, counted vmcnt(4).
  f32x4 acc2[4][4] = {};
  cur = 0;
  for (int t = 0; t < T2; ++t) {
    if (t + 1 < T2) { issueW(g.W2s, t + 1, cur ^ 1); wait_vm4(); }
    else            { wait_vm0(); }
    bf16x8 afr[4], bfr[4];
#pragma unroll
    for (int f = 0; f < 4; f++) {
      const int kc = t * 4 + lhi;
      afr[f] = *(const bf16x8*)&Hsh[(kc * 64 + ((f * 16 + l16) ^ swz(lhi))) * 8];
      bfr[f] = *(const bf16x8*)&Bsh[cur][bpos(lhi, wave * 64 + f * 16 + l16) * 8];
    }
#pragma unroll
    for (int fr = 0; fr < 4; fr++)
#pragma unroll
      for (int fc = 0; fc < 4; fc++)
        acc2[fr][fc] = __builtin_amdgcn_mfma_f32_16x16x32_bf16(afr[fr], bfr[fc], acc2[fr][fc], 0, 0, 0);
    cur ^= 1;
  }

  // ---- epilogue-2: wv | e_new (rank order); final-layer e f32 scattered via iperm
#pragma unroll
  for (int fr = 0; fr < 4; fr++) {
#pragma unroll
    for (int fc = 0; fc < 4; fc++) {
      const int n = wave * 64 + fc * 16 + l16;
#pragma unroll
      for (int r = 0; r < 4; r++) {
        const int lr = fr * 16 + lhi * 4 + r;
        const int row = row0 + lr;
        const float valf = acc2[fr][fc][r];
        if (n < 128) {
          g.wv_out[(size_t)row * 128 + n] = __float2bfloat16(valf + g.b2L[256 + n]);
        } else {
          const float sv = siluf(valf + g.b2L[257 + n]);
          g.e_bf_out[(size_t)row * ED + (n - 128)] = __float2bfloat16(sv);
          if (g.write_e_f32) g.e_f32_out[(size_t)Ei[lr] * ED + (n - 128)] = sv;
        }
      }
    }
  }
}

// ---- LayerNorm (layer 0 only). 4 nodes/block, wave per node.
__global__ __launch_bounds__(256) void ln_k(const float* __restrict__ s,
                                            const float* __restrict__ gl, const float* __restrict__ bl,
                                            __hip_bfloat16* __restrict__ s_ln) {
  const int wave = threadIdx.x >> 6, lane = threadIdx.x & 63;
  const int node = blockIdx.x * 4 + wave;
  const float* srow = s + (size_t)node * SD;
  float x[4], sum = 0.f, sq = 0.f;
#pragma unroll
  for (int i = 0; i < 4; i++) { x[i] = srow[lane * 4 + i]; sum += x[i]; sq += x[i] * x[i]; }
#pragma unroll
  for (int off = 1; off < 64; off <<= 1) { sum += __shfl_xor(sum, off); sq += __shfl_xor(sq, off); }
  const float mu = sum * (1.0f / SD);
  const float var = sq * (1.0f / SD) - mu * mu;
  const float rstd = rsqrtf(var + 1e-5f);
#pragma unroll
  for (int i = 0; i < 4; i++) {
    const int c = lane * 4 + i;
    s_ln[(size_t)node * SD + c] = __float2bfloat16(gl[c] * (x[i] - mu) * rstd + bl[c]);
  }
}

// ---- e conversion into RANK order: thread handles (rank, chunk)
__global__ void cvt_e_k(const float* __restrict__ e, const int* __restrict__ iperm,
                        __hip_bfloat16* __restrict__ ebf) {
  const int idx = blockIdx.x * blockDim.x + threadIdx.x;   // NE*16 threads
  const int pos = idx >> 4, c = idx & 15;
  const int src_e = iperm[pos];
  const float* p = e + (size_t)src_e * ED + c * 8;
  alignas(16) __hip_bfloat16 t8[8];
#pragma unroll
  for (int j = 0; j < 8; j++) t8[j] = __float2bfloat16(p[j]);
  *(uint4*)(ebf + (size_t)pos * ED + c * 8) = *(const uint4*)t8;
}

__global__ void count_k(const int* __restrict__ tgt, int* __restrict__ rawcnt) {
  const int e = blockIdx.x * blockDim.x + threadIdx.x;
  if (e < NE) atomicAdd(&rawcnt[tgt[e]], 1);
}

__global__ __launch_bounds__(256) void scan_k(const int* __restrict__ rawcnt, int* __restrict__ off) {
  __shared__ int ts[256];
  const int tid = threadIdx.x;
  const int base = tid * 32;
  int local[32];
  int s = 0;
#pragma unroll
  for (int i = 0; i < 32; i++) { local[i] = s; s += rawcnt[base + i]; }
  ts[tid] = s;
  __syncthreads();
  if (tid == 0) {
    int acc = 0;
    for (int i = 0; i < 256; i++) { int t = ts[i]; ts[i] = acc; acc += t; }
    off[NN] = acc;
  }
  __syncthreads();
  const int pre = ts[tid];
#pragma unroll
  for (int i = 0; i < 32; i++) off[base + i] = pre + local[i];
}

// ---- scatter: psrc/ptgt/iperm at CSR position
__global__ void scatter_k(const int* __restrict__ tgt, const int* __restrict__ srcp,
                          const int* __restrict__ off, int* __restrict__ cursor,
                          int* __restrict__ psrc, int* __restrict__ ptgt, int* __restrict__ iperm) {
  const int e = blockIdx.x * blockDim.x + threadIdx.x;
  if (e < NE) {
    const int t = tgt[e];
    const int pos = off[t] + atomicAdd(&cursor[t], 1);
    psrc[pos] = srcp[e];
    ptgt[pos] = t;
    iperm[pos] = e;
  }
}

// ---- CSR aggregation: one block per node; sequential payload reads.
// v messages gather from a 3 MB bf16 shadow of v (L2-resident); f32 v stays
// authoritative for the self-add and output.
__global__ __launch_bounds__(256) void agg_k(const int* __restrict__ off, const int* __restrict__ psrc,
                                             const __hip_bfloat16* __restrict__ h,
                                             const __hip_bfloat16* __restrict__ wv,
                                             const float* __restrict__ mp,
                                             const float* __restrict__ rnp,
                                             const float* __restrict__ v_old,
                                             const __hip_bfloat16* __restrict__ vbf_old,
                                             float* __restrict__ v_new,
                                             __hip_bfloat16* __restrict__ vbf_new,
                                             float* __restrict__ Hagg,
                                             float* __restrict__ p_o,
                                             int hasv) {
  const int n = blockIdx.x;
  const int c = threadIdx.x;
  const int e0 = off[n], e1 = off[n + 1];
  const int c3 = c >> 6, ln = c & 63;
  float hs = 0.f, vs = 0.f, ps = 0.f;
  int j = e0;
  for (; j + 2 <= e1; j += 2) {
    const float h0 = __bfloat162float(h[(size_t)j * HIDc + c]);
    const float h1 = __bfloat162float(h[(size_t)(j + 1) * HIDc + c]);
    hs += h0 + h1;
    if (c < 192) {
      const int s0 = psrc[j], s1 = psrc[j + 1];
      float m0 = __bfloat162float(wv[(size_t)j * 128 + 64 + ln]) * rnp[j * 3 + c3];
      float m1 = __bfloat162float(wv[(size_t)(j + 1) * 128 + 64 + ln]) * rnp[(j + 1) * 3 + c3];
      if (hasv) {
        m0 += __bfloat162float(wv[(size_t)j * 128 + ln]) * __bfloat162float(vbf_old[(size_t)s0 * 192 + c]);
        m1 += __bfloat162float(wv[(size_t)(j + 1) * 128 + ln]) * __bfloat162float(vbf_old[(size_t)s1 * 192 + c]);
      }
      vs += m0 + m1;
    } else if (c < 195) {
      ps += mp[j * 3 + (c - 192)] + mp[(j + 1) * 3 + (c - 192)];
    }
  }
  for (; j < e1; j++) {
    hs += __bfloat162float(h[(size_t)j * HIDc + c]);
    if (c < 192) {
      float mv = __bfloat162float(wv[(size_t)j * 128 + 64 + ln]) * rnp[j * 3 + c3];
      if (hasv) mv += __bfloat162float(wv[(size_t)j * 128 + ln]) * __bfloat162float(vbf_old[(size_t)psrc[j] * 192 + c]);
      vs += mv;
    } else if (c < 195) {
      ps += mp[j * 3 + (c - 192)];
    }
  }
  Hagg[(size_t)n * HIDc + c] = hs;
  const float inv = 1.0f / fmaxf((float)(e1 - e0), 1.0f);
  if (c < 192) {
    const float nv = v_old[(size_t)n * 192 + c] + vs * inv;
    v_new[(size_t)n * 192 + c] = nv;
    vbf_new[(size_t)n * 192 + c] = __float2bfloat16(nv);
  } else if (c < 195) {
    p_o[n * 3 + (c - 192)] += ps * inv;
  }
}

__global__ void zero_k(float* __restrict__ ptr, int n) {
  const int i = blockIdx.x * blockDim.x + threadIdx.x;
  if (i < n) ptr[i] = 0.f;
}

// ---- weight prep -> swizzled streams
__global__ void prep_w1abs_k(const float* __restrict__ W1, __hip_bfloat16* __restrict__ W1aS,
                             __hip_bfloat16* __restrict__ W1bS) {
  const int idx = blockIdx.x * blockDim.x + threadIdx.x;
  if (idx >= NL * T2 * 1024) return;
  const int p = idx & 1023, t = (idx >> 10) % T2, l = idx / (T2 * 1024);
  const int kc = p >> 8, n = (p & 255) ^ swz(kc);
  alignas(16) __hip_bfloat16 a8[8], b8[8];
#pragma unroll
  for (int j = 0; j < 8; j++) {
    const int k = t * 32 + kc * 8 + j;
    a8[j] = __float2bfloat16(W1[((size_t)l * DINc + k) * HIDc + n]);
    b8[j] = __float2bfloat16(W1[((size_t)l * DINc + 256 + k) * HIDc + n]);
  }
  *(uint4*)(W1aS + (size_t)idx * 8) = *(const uint4*)a8;
  *(uint4*)(W1bS + (size_t)idx * 8) = *(const uint4*)b8;
}

__global__ void prep_w1es_k(const float* __restrict__ W1, __hip_bfloat16* __restrict__ W1eS) {
  const int idx = blockIdx.x * blockDim.x + threadIdx.x;
  if (idx >= NL * TE * 1024) return;
  const int p = idx & 1023, t = (idx >> 10) % TE, l = idx / (TE * 1024);
  const int kc = p >> 8, n = (p & 255) ^ swz(kc);
  alignas(16) __hip_bfloat16 e8[8];
#pragma unroll
  for (int j = 0; j < 8; j++) {
    const int k = t * 32 + kc * 8 + j;
    const int row = (k < 128) ? (512 + k) : ((k < 132) ? (640 + (k - 128)) : -1);
    e8[j] = __float2bfloat16(row >= 0 ? W1[((size_t)l * DINc + row) * HIDc + n] : 0.f);
  }
  *(uint4*)(W1eS + (size_t)idx * 8) = *(const uint4*)e8;
}

__global__ void prep_w2s_k(const float* __restrict__ W2, __hip_bfloat16* __restrict__ W2sS,
                           __hip_bfloat16* __restrict__ W2aS) {
  const int idx = blockIdx.x * blockDim.x + threadIdx.x;
  if (idx >= NL * T2 * 1024) return;
  const int p = idx & 1023, t = (idx >> 10) & 7, l = idx >> 13;
  const int kc = p >> 8, n = (p & 255) ^ swz(kc);
  const float* W2l = W2 + (size_t)l * HIDc * DOUTc;
  const int cs = (n < 128) ? (256 + n) : (257 + n);
  alignas(16) __hip_bfloat16 s8[8], a8[8];
#pragma unroll
  for (int j = 0; j < 8; j++) {
    const int k = t * 32 + kc * 8 + j;
    s8[j] = __float2bfloat16(W2l[(size_t)k * DOUTc + cs]);
    a8[j] = __float2bfloat16(W2l[(size_t)k * DOUTc + n]);
  }
  *(uint4*)(W2sS + (size_t)idx * 8) = *(const uint4*)s8;
  *(uint4*)(W2aS + (size_t)idx * 8) = *(const uint4*)a8;
}

__global__ void prep_uts_k(const float* __restrict__ U1, const float* __restrict__ U2,
                           __hip_bfloat16* __restrict__ U1S, __hip_bfloat16* __restrict__ U2S) {
  const int idx = blockIdx.x * blockDim.x + threadIdx.x;
  if (idx >= NL * T2 * 1024) return;
  const int p = idx & 1023, t = (idx >> 10) & 7, l = idx >> 13;
  const int kc = p >> 8, n = (p & 255) ^ swz(kc);
  alignas(16) __hip_bfloat16 u1[8], u2[8];
#pragma unroll
  for (int j = 0; j < 8; j++) {
    const int k = t * 32 + kc * 8 + j;
    u1[j] = __float2bfloat16(U1[((size_t)l * HIDc + k) * HIDc + n]);
    u2[j] = __float2bfloat16(U2[((size_t)l * HIDc + k) * HIDc + n]);
  }
  *(uint4*)(U1S + (size_t)idx * 8) = *(const uint4*)u1;
  *(uint4*)(U2S + (size_t)idx * 8) = *(const uint4*)u2;
}

__global__ void prep_w384_k(const float* __restrict__ W2, __hip_bfloat16* __restrict__ w384) {
  const int idx = blockIdx.x * blockDim.x + threadIdx.x;
  if (idx >= NL * HIDc) return;
  const int k = idx & 255, l = idx >> 8;
  w384[idx] = __float2bfloat16(W2[((size_t)l * HIDc + k) * DOUTc + 384]);
}

}  // namespace

extern "C" void kernel_launch(void* const* d_in, const int* in_sizes, int n_in,
                              void* d_out, int out_size, void* d_ws, size_t ws_size,
                              hipStream_t stream) {
  (void)in_sizes; (void)n_in; (void)out_size; (void)ws_size;
  const float* s_in = (const float*)d_in[0];
  const float* v_in = (const float*)d_in[1];
  const float* p_in = (const float*)d_in[2];
  const float* e_in = (const float*)d_in[3];
  const int*   ei   = (const int*)d_in[4];
  const float* ln_g = (const float*)d_in[5];
  const float* ln_b = (const float*)d_in[6];
  const float* W1   = (const float*)d_in[7];
  const float* b1   = (const float*)d_in[8];
  const float* W2   = (const float*)d_in[9];
  const float* b2   = (const float*)d_in[10];
  const float* U1   = (const float*)d_in[11];
  const float* bU1  = (const float*)d_in[12];
  const float* U2   = (const float*)d_in[13];
  const float* bU2  = (const float*)d_in[14];

  float* s_o = (float*)d_out;
  float* v_o = s_o + (size_t)NN * SD;
  float* e_o = v_o + (size_t)NN * 192;
  float* p_o = e_o + (size_t)NE * ED;

  const int* srcp = ei;
  const int* tgtp = ei + NE;

  char* wp = (char*)d_ws;
  auto alloc = [&](size_t bytes) -> char* {
    char* r = wp; wp += (bytes + 255) & ~(size_t)255; return r;
  };
  __hip_bfloat16* s_ln = (__hip_bfloat16*)alloc((size_t)NN * SD * 2);
  __hip_bfloat16* hbuf = (__hip_bfloat16*)alloc((size_t)NE * HIDc * 2);
  __hip_bfloat16* ebf  = (__hip_bfloat16*)alloc((size_t)NE * ED * 2);
  __hip_bfloat16* wvbuf= (__hip_bfloat16*)alloc((size_t)NE * 128 * 2);
  __hip_bfloat16* p1buf= (__hip_bfloat16*)alloc((size_t)NN * SD * 2);
  __hip_bfloat16* p2buf= (__hip_bfloat16*)alloc((size_t)NN * SD * 2);
  __hip_bfloat16* vbf0 = (__hip_bfloat16*)alloc((size_t)NN * 192 * 2);
  __hip_bfloat16* vbf1 = (__hip_bfloat16*)alloc((size_t)NN * 192 * 2);
  float* rnpbuf= (float*)alloc((size_t)NE * 3 * 4);
  float* Hagg  = (float*)alloc((size_t)NN * SD * 4);
  float* vprev = (float*)alloc((size_t)NN * 192 * 4);
  float* mpbuf = (float*)alloc((size_t)NE * 3 * 4);
  float* zerobias = (float*)alloc(256 * 4);
  int*   rawcnt= (int*)alloc((size_t)NN * 4);
  int*   offb  = (int*)alloc((size_t)(NN + 1) * 4);
  int*   cursor= (int*)alloc((size_t)NN * 4);
  int*   psrcb = (int*)alloc((size_t)NE * 4);
  int*   ptgtb = (int*)alloc((size_t)NE * 4);
  int*   ipermb= (int*)alloc((size_t)NE * 4);
  __hip_bfloat16* W1aS = (__hip_bfloat16*)alloc((size_t)NL * T2 * 1024 * 8 * 2);
  __hip_bfloat16* W1bS = (__hip_bfloat16*)alloc((size_t)NL * T2 * 1024 * 8 * 2);
  __hip_bfloat16* W1eS = (__hip_bfloat16*)alloc((size_t)NL * TE * 1024 * 8 * 2);
  __hip_bfloat16* W2sS = (__hip_bfloat16*)alloc((size_t)NL * T2 * 1024 * 8 * 2);
  __hip_bfloat16* W2aS = (__hip_bfloat16*)alloc((size_t)NL * T2 * 1024 * 8 * 2);
  __hip_bfloat16* U1S  = (__hip_bfloat16*)alloc((size_t)NL * T2 * 1024 * 8 * 2);
  __hip_bfloat16* U2S  = (__hip_bfloat16*)alloc((size_t)NL * T2 * 1024 * 8 * 2);
  __hip_bfloat16* w384 = (__hip_bfloat16*)alloc((size_t)NL * HIDc * 2);

  hipMemcpyAsync(s_o, s_in, (size_t)NN * SD * 4, hipMemcpyDeviceToDevice, stream);
  hipMemcpyAsync(vprev, v_in, (size_t)NN * 192 * 4, hipMemcpyDeviceToDevice, stream);
  hipMemcpyAsync(p_o, p_in, (size_t)NN * 3 * 4, hipMemcpyDeviceToDevice, stream);

  prep_w1abs_k<<<(NL * T2 * 1024 + 255) / 256, 256, 0, stream>>>(W1, W1aS, W1bS);
  prep_w1es_k<<<(NL * TE * 1024 + 255) / 256, 256, 0, stream>>>(W1, W1eS);
  prep_w2s_k<<<(NL * T2 * 1024 + 255) / 256, 256, 0, stream>>>(W2, W2sS, W2aS);
  prep_uts_k<<<(NL * T2 * 1024 + 255) / 256, 256, 0, stream>>>(U1, U2, U1S, U2S);
  prep_w384_k<<<(NL * HIDc + 255) / 256, 256, 0, stream>>>(W2, w384);
  zero_k<<<1, 256, 0, stream>>>(zerobias, 256);

  // ---- CSR build (once; edge_index layer-invariant), then permuted e conversion
  zero_k<<<(NN + 255) / 256, 256, 0, stream>>>((float*)rawcnt, NN);
  zero_k<<<(NN + 255) / 256, 256, 0, stream>>>((float*)cursor, NN);
  count_k<<<NE / 256, 256, 0, stream>>>(tgtp, rawcnt);
  scan_k<<<1, 256, 0, stream>>>(rawcnt, offb);
  scatter_k<<<NE / 256, 256, 0, stream>>>(tgtp, srcp, offb, cursor, psrcb, ptgtb, ipermb);
  cvt_e_k<<<NE * 16 / 256, 256, 0, stream>>>(e_in, ipermb, ebf);

  // ---- layer 0: LN + P1/P2 (subsequent layers fold these into node3)
  ln_k<<<NN / 4, 256, 0, stream>>>(s_o, ln_g, ln_b, s_ln);
  GemmArgs gp{};
  gp.Wt = W1aS; gp.bias = b1; gp.bf_out = p1buf;
  gp.Wtb = W1bS; gp.biasb = zerobias; gp.bf_outb = p2buf;
  gp.Abf = s_ln; gp.dual = 1;
  gemm_k<256, 64><<<2 * NN / 64, 256, 0, stream>>>(gp);

  for (int l = 0; l < NL; l++) {
    // fused edge kernel (CSR-ordered): attrs + h + out2, all payloads streaming
    FusedArgs gf{};
    gf.W1e = W1eS + (size_t)l * TE * 1024 * 8;
    gf.W2s = W2sS + (size_t)l * T2 * 1024 * 8;
    gf.b2L = b2 + l * DOUTc;
    gf.psrc = psrcb; gf.ptgt = ptgtb; gf.iperm = ipermb;
    gf.pos = p_o; gf.e_bf = ebf;
    gf.p1 = p1buf; gf.p2 = p2buf; gf.w384 = w384 + l * HIDc;
    gf.rnp = rnpbuf; gf.mp = mpbuf;
    gf.h_out = hbuf; gf.wv_out = wvbuf; gf.e_bf_out = ebf; gf.e_f32_out = e_o;
    gf.write_e_f32 = (l == NL - 1) ? 1 : 0;
    fused_k<<<NE / 64, 256, 0, stream>>>(gf);

    // v ping-pong (f32 + bf16 shadow): 5 layers -> final f32 lands in v_o.
    const float* vold = (l & 1) ? (const float*)v_o : (const float*)vprev;
    float* vnew = (l & 1) ? vprev : v_o;
    const __hip_bfloat16* vbold = (l & 1) ? (const __hip_bfloat16*)vbf1 : (const __hip_bfloat16*)vbf0;
    __hip_bfloat16* vbnew = (l & 1) ? vbf0 : vbf1;
    agg_k<<<NN, 256, 0, stream>>>(offb, psrcb, hbuf, wvbuf, mpbuf, rnpbuf,
                                  vold, vbold, vnew, vbnew, Hagg, p_o, (l > 0) ? 1 : 0);

    // fused node MLP (+ next-layer LN/P1/P2 when l<4)
    Node3Args gn{};
    gn.W2a = W2aS + (size_t)l * T2 * 1024 * 8;
    gn.U1s = U1S + (size_t)l * T2 * 1024 * 8;
    gn.U2s = U2S + (size_t)l * T2 * 1024 * 8;
    gn.b2L = b2 + l * DOUTc; gn.bU1 = bU1 + l * HIDc; gn.bU2 = bU2 + l * HIDc;
    gn.Hagg = Hagg; gn.rawcnt = rawcnt; gn.s_out = s_o;
    if (l < NL - 1) {
      gn.W1an = W1aS + (size_t)(l + 1) * T2 * 1024 * 8;
      gn.W1bn = W1bS + (size_t)(l + 1) * T2 * 1024 * 8;
      gn.b1n = b1 + (l + 1) * HIDc;
      gn.lng = ln_g + (l + 1) * SD; gn.lnb = ln_b + (l + 1) * SD;
      gn.p1 = p1buf; gn.p2 = p2buf;
      node3_k<0><<<NN / 32, 256, 0, stream>>>(gn);
    } else {
      node3_k<1><<<NN / 32, 256, 0, stream>>>(gn);
    }
  }
}